// Round 7
// baseline (223.909 us; speedup 1.0000x reference)
//
#include <hip/hip_runtime.h>

constexpr int Bn = 4, NL = 1024, HWn = 4096, NH = 8;

typedef __attribute__((ext_vector_type(8))) short bf16x8;
typedef __attribute__((ext_vector_type(4))) float f32x4;
#define MFMA16 __builtin_amdgcn_mfma_f32_16x16x32_bf16

extern "C" __device__ float __ocml_native_exp2_f32(float);

__device__ __forceinline__ float b2f(unsigned short u) {
  union { unsigned int i; float f; } x; x.i = ((unsigned int)u) << 16; return x.f;
}
__device__ __forceinline__ unsigned short f2b(float f) {
  union { float f; unsigned int i; } x; x.f = f;
  unsigned int r = x.i + 0x7fffu + ((x.i >> 16) & 1u);   // RNE
  return (unsigned short)(r >> 16);
}
__device__ __forceinline__ unsigned short f2b_rtz(float f) {
  union { float f; unsigned int i; } x; x.f = f;
  return (unsigned short)(x.i >> 16);
}

// ---------- f32 -> bf16 ----------
__global__ __launch_bounds__(256) void conv_bf16(const float* __restrict__ src,
    unsigned short* __restrict__ dst, int n)
{
  int i = (blockIdx.x * 256 + threadIdx.x) * 4;
  if (i < n) {
    float4 v = *(const float4*)(src + i);
    ushort4 o; o.x = f2b(v.x); o.y = f2b(v.y); o.z = f2b(v.z); o.w = f2b(v.w);
    *(ushort4*)(dst + i) = o;
  }
}

// ---------- weight conversions: Wk/Wv/Wq -> bf16; Ww -> hi/lo bf16 split ----------
__global__ __launch_bounds__(256) void conv_w4(const float* __restrict__ Wk,
    const float* __restrict__ Wv, const float* __restrict__ Wq,
    const float* __restrict__ Ww,
    unsigned short* __restrict__ wkb, unsigned short* __restrict__ wvb,
    unsigned short* __restrict__ wqb,
    unsigned short* __restrict__ wwh, unsigned short* __restrict__ wwl)
{
  int i = (blockIdx.x * 256 + threadIdx.x) * 4;
  if (blockIdx.y == 3) {
    if (i >= 65536) return;
    float4 v = *(const float4*)(Ww + i);
    ushort4 hi, lo;
    hi.x = f2b(v.x); lo.x = f2b(v.x - b2f(hi.x));
    hi.y = f2b(v.y); lo.y = f2b(v.y - b2f(hi.y));
    hi.z = f2b(v.z); lo.z = f2b(v.z - b2f(hi.z));
    hi.w = f2b(v.w); lo.w = f2b(v.w - b2f(hi.w));
    *(ushort4*)(wwh + i) = hi;
    *(ushort4*)(wwl + i) = lo;
    return;
  }
  const float* src = blockIdx.y == 0 ? Wk : (blockIdx.y == 1 ? Wv : Wq);
  unsigned short* dst = blockIdx.y == 0 ? wkb : (blockIdx.y == 1 ? wvb : wqb);
  float4 v = *(const float4*)(src + i);
  ushort4 o; o.x = f2b(v.x); o.y = f2b(v.y); o.z = f2b(v.z); o.w = f2b(v.w);
  *(ushort4*)(dst + i) = o;
}

// ---------- unified 128x128 MFMA GEMM (LDS-staged), K=512 (verified R5/R6) ----------
__global__ __launch_bounds__(256, 2) void gemm128(
    const unsigned short* __restrict__ xbf, const unsigned short* __restrict__ lbf,
    const unsigned short* __restrict__ wkb, const unsigned short* __restrict__ wvb,
    const unsigned short* __restrict__ wqb,
    const float* __restrict__ bk, const float* __restrict__ bv, const float* __restrict__ bq,
    unsigned short* __restrict__ khb, unsigned short* __restrict__ vhb,
    unsigned short* __restrict__ qbuf)
{
  __shared__ unsigned short As[128 * 32];
  __shared__ unsigned short Bs[128 * 32];
  const int id = blockIdx.x;
  const int mode = id < 256 ? 0 : (id < 512 ? 1 : 2);   // 0=K 1=V 2=Q
  const int local = id - (mode == 0 ? 0 : (mode == 1 ? 256 : 512));
  const int rb = local >> 1, cb = local & 1;
  const int m0 = rb * 128, n0 = cb * 128;
  const unsigned short* A = (mode == 2) ? lbf : xbf;
  const unsigned short* W = (mode == 0) ? wkb : (mode == 1 ? wvb : wqb);
  const float* bias = (mode == 0) ? bk : (mode == 1 ? bv : bq);

  const int tid = threadIdx.x, w = tid >> 6, lane = tid & 63;
  const int quad = lane >> 4, l15 = lane & 15;
  const int wr = w >> 1, wc = w & 1;

  const int p0 = tid, p1 = tid + 256;
  const int am0 = p0 >> 2, ak0 = (p0 & 3) * 8;
  const int am1 = p1 >> 2, ak1 = (p1 & 3) * 8;

  f32x4 acc[4][4];
#pragma unroll
  for (int i = 0; i < 4; ++i)
#pragma unroll
    for (int j = 0; j < 4; ++j) acc[i][j] = (f32x4){0.f, 0.f, 0.f, 0.f};

  bf16x8 ar0 = *(const bf16x8*)(A + (size_t)(m0 + am0) * 512 + ak0);
  bf16x8 ar1 = *(const bf16x8*)(A + (size_t)(m0 + am1) * 512 + ak1);
  bf16x8 br0 = *(const bf16x8*)(W + (size_t)(n0 + am0) * 512 + ak0);
  bf16x8 br1 = *(const bf16x8*)(W + (size_t)(n0 + am1) * 512 + ak1);

  for (int kt = 0; kt < 16; ++kt) {
    __syncthreads();
    *(bf16x8*)&As[p0 * 8] = ar0;
    *(bf16x8*)&As[p1 * 8] = ar1;
    *(bf16x8*)&Bs[p0 * 8] = br0;
    *(bf16x8*)&Bs[p1 * 8] = br1;
    if (kt < 15) {
      int k0 = (kt + 1) * 32;
      ar0 = *(const bf16x8*)(A + (size_t)(m0 + am0) * 512 + k0 + ak0);
      ar1 = *(const bf16x8*)(A + (size_t)(m0 + am1) * 512 + k0 + ak1);
      br0 = *(const bf16x8*)(W + (size_t)(n0 + am0) * 512 + k0 + ak0);
      br1 = *(const bf16x8*)(W + (size_t)(n0 + am1) * 512 + k0 + ak1);
    }
    __syncthreads();
    bf16x8 af[4], bf[4];
#pragma unroll
    for (int fr = 0; fr < 4; ++fr)
      af[fr] = *(const bf16x8*)&As[(wr * 64 + fr * 16 + l15) * 32 + quad * 8];
#pragma unroll
    for (int fc = 0; fc < 4; ++fc)
      bf[fc] = *(const bf16x8*)&Bs[(wc * 64 + fc * 16 + l15) * 32 + quad * 8];
#pragma unroll
    for (int fr = 0; fr < 4; ++fr)
#pragma unroll
      for (int fc = 0; fc < 4; ++fc)
        acc[fr][fc] = MFMA16(af[fr], bf[fc], acc[fr][fc], 0, 0, 0);
  }

  float bb[4];
#pragma unroll
  for (int fc = 0; fc < 4; ++fc) bb[fc] = bias[n0 + wc * 64 + fc * 16 + l15];
  unsigned short* dst = (mode == 0) ? khb : (mode == 1 ? vhb : qbuf);
#pragma unroll
  for (int fr = 0; fr < 4; ++fr) {
#pragma unroll
    for (int fc = 0; fc < 4; ++fc) {
      int col = n0 + wc * 64 + fc * 16 + l15;
#pragma unroll
      for (int r = 0; r < 4; ++r) {
        int row = m0 + wr * 64 + fr * 16 + quad * 4 + r;
        unsigned short val = f2b(acc[fr][fc][r] + bb[fc]);
        if (mode == 2) {
          dst[(size_t)row * 256 + col] = val;
        } else {
          int b = row >> 12, n = row & 4095, h = col >> 5, d = col & 31;
          dst[((size_t)(b * 8 + h) * 4096 + n) * 32 + d] = val;
        }
      }
    }
  }
}

// ---------- merged K-stats + V-sums. grid (64, 8) ----------
__global__ __launch_bounds__(256) void kvstats(const unsigned short* __restrict__ khb,
    const unsigned short* __restrict__ vhb,
    float* __restrict__ ksum, float* __restrict__ kss, float* __restrict__ vcs)
{
  const int which = blockIdx.x >> 5, bh = blockIdx.x & 31, seg = blockIdx.y;
  const int t = threadIdx.x, d = t & 31, g = t >> 5;
  __shared__ float rs[256], rss[256];
  if (which == 0) {
    const unsigned short* base = khb + (size_t)bh * 131072 + (size_t)seg * 512 * 32;
    float s = 0.f, ss = 0.f;
    for (int i = 0; i < 64; ++i) {
      float v = b2f(base[(size_t)(g + i * 8) * 32 + d]);
      s += v; ss += v * v;
    }
    rs[t] = s; rss[t] = ss;
    __syncthreads();
    if (t < 32) {
      float a = 0.f, b = 0.f;
      for (int g2 = 0; g2 < 8; ++g2) { a += rs[t + g2 * 32]; b += rss[t + g2 * 32]; }
      atomicAdd(&ksum[bh * 32 + t], a);
      atomicAdd(&kss[bh * 32 + t], b);
    }
  } else {
    const unsigned short* base = vhb + (size_t)bh * 131072 + (size_t)seg * 512 * 32;
    float s = 0.f;
    for (int i = 0; i < 64; ++i) s += b2f(base[(size_t)(g + i * 8) * 32 + d]);
    rs[t] = s;
    __syncthreads();
    if (t < 32) {
      float a = 0.f;
      for (int g2 = 0; g2 < 8; ++g2) a += rs[t + g2 * 32];
      vcs[seg * 1024 + bh * 32 + t] = a;
    }
  }
}

__global__ __launch_bounds__(256) void kfinal(const float* __restrict__ ksum,
    const float* __restrict__ kss, float* __restrict__ krstd)
{
  int i = blockIdx.x * 256 + threadIdx.x;
  float m = ksum[i] * (1.f / 4096.f);
  float var = kss[i] * (1.f / 4096.f) - m * m;
  krstd[i] = rsqrtf(var + 1e-5f);
}

// ---------- pack V head-major -> frag-major ----------
__global__ __launch_bounds__(256) void vpack(const unsigned short* __restrict__ vh,
    unsigned short* __restrict__ vfrag)
{
  __shared__ unsigned short vt[256][42];
  const int bh = blockIdx.x >> 4, slab = blockIdx.x & 15;
  const unsigned short* src = vh + ((size_t)bh * 4096 + slab * 256) * 32;
  const int t = threadIdx.x;
#pragma unroll
  for (int i = 0; i < 4; ++i) {
    int p = i * 256 + t;
    int n = p >> 2, piece = p & 3;
    uint4 v = *(const uint4*)(src + (size_t)n * 32 + piece * 8);
    unsigned int* lrow = (unsigned int*)&vt[n][piece * 8];
    lrow[0] = v.x; lrow[1] = v.y; lrow[2] = v.z; lrow[3] = v.w;
  }
  __syncthreads();
#pragma unroll
  for (int i = 0; i < 4; ++i) {
    int op = i * 256 + t;
    int lanep = op & 63, rest = op >> 6;
    int dvt = rest & 1, kh2 = (rest >> 1) & 1, chunkl = rest >> 2;
    int lq = lanep >> 4, ll = lanep & 15;
    unsigned short o[8];
#pragma unroll
    for (int j = 0; j < 8; ++j)
      o[j] = vt[chunkl * 64 + kh2 * 32 + lq * 8 + j][dvt * 16 + ll];
    size_t dst = ((((size_t)bh * 64 + slab * 4 + chunkl) * 2 + kh2) * 2 + dvt) * 512 + lanep * 8;
    *(bf16x8*)(vfrag + dst) = *(const bf16x8*)o;
  }
}

// ---------- MFMA flash attention v3: small LDS, exp2, per-lf P pipeline ----------
// grid (32, 4, 8) = (bh, lsuper, half); block 256 (4 waves; wave = 64 l-rows)
__global__ __launch_bounds__(256, 4) void attn3(const unsigned short* __restrict__ qbuf,
    const unsigned short* __restrict__ khb, const unsigned short* __restrict__ vfrag,
    const float* __restrict__ krstd, const float* __restrict__ vcs,
    float* __restrict__ po, float* __restrict__ pd)
{
  const int bh = blockIdx.x, b = bh >> 3, h = bh & 7;
  const int lsuper = blockIdx.y, half = blockIdx.z;
  const int tid = threadIdx.x, w = tid >> 6, lane = tid & 63;
  const int quad = lane >> 4, l15 = lane & 15;

  __shared__ unsigned short kb_s[2048];
  __shared__ unsigned short vb_s[2048];
  __shared__ unsigned short ps[4][16][72];   // per-wave, reused per lf

  // Q A-frags with krstd * (1/16) * log2(e) folded in (softmax base-2)
  bf16x8 qa[4];
  {
    float fold[8];
    const float* rp = krstd + bh * 32 + quad * 8;
#pragma unroll
    for (int j = 0; j < 8; ++j) fold[j] = rp[j] * (0.0625f * 1.44269504f);
#pragma unroll
    for (int lf = 0; lf < 4; ++lf) {
      int l = lsuper * 256 + w * 64 + lf * 16 + l15;
      bf16x8 qr = *(const bf16x8*)(qbuf + ((size_t)(b * NL + l)) * 256 + h * 32 + quad * 8);
      const unsigned short* qq = (const unsigned short*)&qr;
      unsigned short tmp[8];
#pragma unroll
      for (int j = 0; j < 8; ++j) tmp[j] = f2b(b2f(qq[j]) * fold[j]);
      qa[lf] = *(const bf16x8*)tmp;
    }
  }

  float drow[4][4];
  f32x4 acc[4][2];
#pragma unroll
  for (int lf = 0; lf < 4; ++lf) {
#pragma unroll
    for (int r = 0; r < 4; ++r) drow[lf][r] = 0.f;
    acc[lf][0] = (f32x4){0.f,0.f,0.f,0.f};
    acc[lf][1] = (f32x4){0.f,0.f,0.f,0.f};
  }

  const unsigned short* kcbase = khb + (size_t)bh * 131072 + (size_t)half * 512 * 32;
  const unsigned short* vcbase = vfrag + (size_t)bh * 131072 + (size_t)half * 8 * 2048;

  bf16x8 kreg = *(const bf16x8*)(kcbase + tid * 8);
  bf16x8 vreg = *(const bf16x8*)(vcbase + tid * 8);

  for (int c = 0; c < 8; ++c) {
    __syncthreads();
    *(bf16x8*)&kb_s[tid * 8] = kreg;
    *(bf16x8*)&vb_s[tid * 8] = vreg;
    if (c < 7) {
      kreg = *(const bf16x8*)(kcbase + (c + 1) * 2048 + tid * 8);
      vreg = *(const bf16x8*)(vcbase + (c + 1) * 2048 + tid * 8);
    }
    __syncthreads();

    bf16x8 kb[4];
#pragma unroll
    for (int t = 0; t < 4; ++t)
      kb[t] = *(const bf16x8*)&kb_s[(t * 16 + l15) * 32 + quad * 8];
    bf16x8 vb[4];
#pragma unroll
    for (int i = 0; i < 4; ++i)
      vb[i] = *(const bf16x8*)&vb_s[i * 512 + lane * 8];

    f32x4 z = (f32x4){0.f,0.f,0.f,0.f};
#pragma unroll
    for (int lf = 0; lf < 4; ++lf) {
      f32x4 sv[4];
#pragma unroll
      for (int t = 0; t < 4; ++t) sv[t] = MFMA16(qa[lf], kb[t], z, 0, 0, 0);
#pragma unroll
      for (int r = 0; r < 4; ++r) {
        float e0 = __ocml_native_exp2_f32(sv[0][r]);
        float e1 = __ocml_native_exp2_f32(sv[1][r]);
        float e2 = __ocml_native_exp2_f32(sv[2][r]);
        float e3 = __ocml_native_exp2_f32(sv[3][r]);
        drow[lf][r] += (e0 + e1) + (e2 + e3);
        int row = quad * 4 + r;
        ps[w][row][l15]      = f2b_rtz(e0 - 1.0f);
        ps[w][row][16 + l15] = f2b_rtz(e1 - 1.0f);
        ps[w][row][32 + l15] = f2b_rtz(e2 - 1.0f);
        ps[w][row][48 + l15] = f2b_rtz(e3 - 1.0f);
      }
      asm volatile("s_waitcnt lgkmcnt(0)" ::: "memory");
#pragma unroll
      for (int kh2 = 0; kh2 < 2; ++kh2) {
        bf16x8 pa = *(const bf16x8*)&ps[w][l15][kh2 * 32 + quad * 8];
#pragma unroll
        for (int dvt = 0; dvt < 2; ++dvt)
          acc[lf][dvt] = MFMA16(pa, vb[kh2 * 2 + dvt], acc[lf][dvt], 0, 0, 0);
      }
      asm volatile("s_waitcnt lgkmcnt(0)" ::: "memory");   // pa reads done before next lf overwrites
    }
  }

  const float* vc = vcs + half * 1024 + bh * 32;
  float cs0 = vc[l15], cs1 = vc[16 + l15];
#pragma unroll
  for (int lf = 0; lf < 4; ++lf)
#pragma unroll
    for (int r = 0; r < 4; ++r) {
      acc[lf][0][r] += cs0;
      acc[lf][1][r] += cs1;
    }

  const size_t PDo = (size_t)half * 32768 + (size_t)bh * 1024;
#pragma unroll
  for (int lf = 0; lf < 4; ++lf) {
#pragma unroll
    for (int r = 0; r < 4; ++r) {
      float sv = drow[lf][r];
      sv += __shfl_xor(sv, 1, 16);
      sv += __shfl_xor(sv, 2, 16);
      sv += __shfl_xor(sv, 4, 16);
      sv += __shfl_xor(sv, 8, 16);
      int l = lsuper * 256 + w * 64 + lf * 16 + quad * 4 + r;
      size_t base = (PDo + l) * 32;
      po[base + l15]      = acc[lf][0][r];
      po[base + 16 + l15] = acc[lf][1][r];
      if (l15 == 0) pd[PDo + l] = sv;
    }
  }
}

// ---------- combine 8 n-eighths -> ao hi/lo bf16 ----------
__global__ __launch_bounds__(256) void combine8(const float* __restrict__ po,
    const float* __restrict__ pd, unsigned short* __restrict__ aoh,
    unsigned short* __restrict__ aol)
{
  int gid = blockIdx.x * 256 + threadIdx.x;
  int dv = gid & 31, l = (gid >> 5) & (NL - 1), h = (gid >> 15) & 7, b = gid >> 18;
  size_t r = ((size_t)(b * 8 + h)) * 1024 + l;
  float d = 0.f, o = 0.f;
#pragma unroll
  for (int half = 0; half < 8; ++half) {
    size_t rr = (size_t)half * 32768 + r;
    d += pd[rr];
    o += po[rr * 32 + dv];
  }
  o = o / d;
  unsigned short hi = f2b(o);
  size_t idx = ((size_t)(b * NL) + l) * 256 + h * 32 + dv;
  aoh[idx] = hi;
  aol[idx] = f2b(o - b2f(hi));
}

// ---------- proj GEMM via MFMA hi/lo (3 passes), K=256. grid (64, 2) ----------
__global__ __launch_bounds__(256) void gemm_proj(
    const unsigned short* __restrict__ aoh, const unsigned short* __restrict__ aol,
    const unsigned short* __restrict__ wwh, const unsigned short* __restrict__ wwl,
    const float* __restrict__ bw, float* __restrict__ pj)
{
  __shared__ unsigned short As[64 * 32];
  __shared__ unsigned short Bs[128 * 32];
  const int bm = blockIdx.x * 64, bn = blockIdx.y * 128;
  const int tid = threadIdx.x, w = tid >> 6, lane = tid & 63;
  const int quad = lane >> 4, l15 = lane & 15;
  const int wr = w >> 1, wc = w & 1;
  const int arow = tid >> 2, apiece = (tid & 3) * 8;

  f32x4 acc[2][4];
#pragma unroll
  for (int i = 0; i < 2; ++i)
#pragma unroll
    for (int j = 0; j < 4; ++j) acc[i][j] = (f32x4){0.f, 0.f, 0.f, 0.f};

  for (int pair = 0; pair < 3; ++pair) {
    const unsigned short* A = (pair == 1) ? aol : aoh;
    const unsigned short* Bm = (pair == 2) ? wwl : wwh;
    for (int kt = 0; kt < 8; ++kt) {
      int k0 = kt * 32;
      __syncthreads();
      *(bf16x8*)&As[tid * 8] = *(const bf16x8*)(A + (size_t)(bm + arow) * 256 + k0 + apiece);
#pragma unroll
      for (int it = 0; it < 2; ++it) {
        int p = tid + it * 256;
        int brow = p >> 2, bpiece = (p & 3) * 8;
        *(bf16x8*)&Bs[p * 8] = *(const bf16x8*)(Bm + (size_t)(bn + brow) * 256 + k0 + bpiece);
      }
      __syncthreads();
      bf16x8 af[2], bf[4];
#pragma unroll
      for (int fr = 0; fr < 2; ++fr)
        af[fr] = *(const bf16x8*)&As[(wr * 32 + fr * 16 + l15) * 32 + quad * 8];
#pragma unroll
      for (int fc = 0; fc < 4; ++fc)
        bf[fc] = *(const bf16x8*)&Bs[(wc * 64 + fc * 16 + l15) * 32 + quad * 8];
#pragma unroll
      for (int fr = 0; fr < 2; ++fr)
#pragma unroll
        for (int fc = 0; fc < 4; ++fc)
          acc[fr][fc] = MFMA16(af[fr], bf[fc], acc[fr][fc], 0, 0, 0);
    }
  }

#pragma unroll
  for (int fr = 0; fr < 2; ++fr)
#pragma unroll
    for (int fc = 0; fc < 4; ++fc) {
      int col = bn + wc * 64 + fc * 16 + l15;
      float bb = bw[col];
#pragma unroll
      for (int r = 0; r < 4; ++r) {
        int row = bm + wr * 32 + fr * 16 + quad * 4 + r;
        pj[(size_t)row * 256 + col] = acc[fr][fc][r] + bb;
      }
    }
}

// ---------- proj instance-norm stats. grid (B, 64), 16 rows/block ----------
__global__ __launch_bounds__(256) void stats_kernel(const float* __restrict__ X,
    long batchStride, int rowsPerBlock,
    float* __restrict__ sum, float* __restrict__ sumsq)
{
  const int b = blockIdx.x, c = threadIdx.x;
  const long r0 = (long)blockIdx.y * rowsPerBlock;
  const float* base = X + (long)b * batchStride + r0 * 256 + c;
  float s = 0.f, ss = 0.f;
  for (int r = 0; r < rowsPerBlock; ++r) {
    float v = base[(long)r * 256];
    s += v; ss += v * v;
  }
  atomicAdd(&sum[b * 256 + c], s);
  atomicAdd(&sumsq[b * 256 + c], ss);
}

__global__ __launch_bounds__(256) void finalize_stats(const float* __restrict__ sum,
    const float* __restrict__ sumsq, float invR,
    float* __restrict__ mean, float* __restrict__ rstd)
{
  int i = blockIdx.x * 256 + threadIdx.x;
  float m = sum[i] * invR;
  float v = sumsq[i] * invR - m * m;
  mean[i] = m;
  rstd[i] = rsqrtf(v + 1e-5f);
}

__global__ __launch_bounds__(256) void final_out(const float* __restrict__ proj,
    const float* __restrict__ mean, const float* __restrict__ rstd,
    float* __restrict__ out)
{
  const int b = blockIdx.x, o = threadIdx.x;
  const int l1 = blockIdx.y * 16;
  const float m = mean[b * 256 + o], r = rstd[b * 256 + o];
  for (int i = 0; i < 16; ++i) {
    size_t idx = ((size_t)(b * NL + l1 + i)) * 256 + o;
    out[idx] = (proj[idx] - m) * r;
  }
}

extern "C" void kernel_launch(void* const* d_in, const int* in_sizes, int n_in,
                              void* d_out, int out_size, void* d_ws, size_t ws_size,
                              hipStream_t stream)
{
  const float* l  = (const float*)d_in[0];
  const float* x  = (const float*)d_in[1];
  const float* Wq = (const float*)d_in[2];
  const float* bq = (const float*)d_in[3];
  const float* Wk = (const float*)d_in[4];
  const float* bk = (const float*)d_in[5];
  const float* Wv = (const float*)d_in[6];
  const float* bv = (const float*)d_in[7];
  const float* Ww = (const float*)d_in[8];
  const float* bw = (const float*)d_in[9];
  float* out = (float*)d_out;

  unsigned short* up = (unsigned short*)d_ws;
  unsigned short* xbf   = up;                         // 8,388,608
  unsigned short* lbf   = xbf   + 8388608;            // 2,097,152
  unsigned short* wkb   = lbf   + 2097152;            // 131,072
  unsigned short* wvb   = wkb   + 131072;
  unsigned short* wqb   = wvb   + 131072;
  unsigned short* qbuf  = wqb   + 131072;             // 1,048,576
  unsigned short* khb   = qbuf  + 1048576;            // 4,194,304
  unsigned short* vhb   = khb   + 4194304;
  unsigned short* vfrag = vhb   + 4194304;
  unsigned short* aoh   = vfrag + 4194304;            // 1,048,576
  unsigned short* aol   = aoh   + 1048576;
  unsigned short* wwh   = aol   + 1048576;            // 65,536
  unsigned short* wwl   = wwh   + 65536;
  // ushort total = 26,738,688 -> 53,477,376 bytes
  float* F     = (float*)((char*)d_ws + 53477376);
  float* krstd = F;                                   // 1024
  float* vcs   = krstd + 1024;                        // 8192
  float* po    = vcs + 8192;                          // 8,388,608
  float* pd    = po + 8388608;                        // 262,144
  float* pj    = pd + 262144;                         // 1,048,576
  float* st    = pj + 1048576;                        // 6144
  float* ksum  = st;          float* kss   = st + 1024;
  float* psum  = st + 2048;   float* psq   = st + 3072;
  float* pmean = st + 4096;   float* prstd = st + 5120;

  hipMemsetAsync(st, 0, 4096 * sizeof(float), stream);

  dim3 blk(256);
  conv_bf16<<<8192, blk, 0, stream>>>(x,  xbf, 8388608);
  conv_bf16<<<2048, blk, 0, stream>>>(l,  lbf, 2097152);
  conv_w4<<<dim3(128, 4), blk, 0, stream>>>(Wk, Wv, Wq, Ww, wkb, wvb, wqb, wwh, wwl);
  gemm128<<<576, blk, 0, stream>>>(xbf, lbf, wkb, wvb, wqb, bk, bv, bq, khb, vhb, qbuf);
  kvstats<<<dim3(64, 8), blk, 0, stream>>>(khb, vhb, ksum, kss, vcs);
  kfinal<<<4, blk, 0, stream>>>(ksum, kss, krstd);
  vpack<<<512, blk, 0, stream>>>(vhb, vfrag);
  attn3<<<dim3(32, 4, 8), blk, 0, stream>>>(qbuf, khb, vfrag, krstd, vcs, po, pd);
  combine8<<<4096, blk, 0, stream>>>(po, pd, aoh, aol);
  gemm_proj<<<dim3(64, 2), blk, 0, stream>>>(aoh, aol, wwh, wwl, bw, pj);
  stats_kernel<<<dim3(4, 64), blk, 0, stream>>>(pj, (long)NL * 256, 16, psum, psq);
  finalize_stats<<<4, blk, 0, stream>>>(psum, psq, 1.0f / NL, pmean, prstd);
  final_out<<<dim3(4, 64), blk, 0, stream>>>(pj, pmean, prstd, out);
}

// Round 8
// 218.639 us; speedup vs baseline: 1.0241x; 1.0241x over previous
//
#include <hip/hip_runtime.h>

constexpr int Bn = 4, NL = 1024, HWn = 4096, NH = 8;

typedef __attribute__((ext_vector_type(8))) short bf16x8;
typedef __attribute__((ext_vector_type(4))) float f32x4;
#define MFMA16 __builtin_amdgcn_mfma_f32_16x16x32_bf16

extern "C" __device__ float __ocml_native_exp2_f32(float);

__device__ __forceinline__ float b2f(unsigned short u) {
  union { unsigned int i; float f; } x; x.i = ((unsigned int)u) << 16; return x.f;
}
__device__ __forceinline__ unsigned short f2b(float f) {
  union { float f; unsigned int i; } x; x.f = f;
  unsigned int r = x.i + 0x7fffu + ((x.i >> 16) & 1u);   // RNE
  return (unsigned short)(r >> 16);
}

// ---------- f32 -> bf16 ----------
__global__ __launch_bounds__(256) void conv_bf16(const float* __restrict__ src,
    unsigned short* __restrict__ dst, int n)
{
  int i = (blockIdx.x * 256 + threadIdx.x) * 4;
  if (i < n) {
    float4 v = *(const float4*)(src + i);
    ushort4 o; o.x = f2b(v.x); o.y = f2b(v.y); o.z = f2b(v.z); o.w = f2b(v.w);
    *(ushort4*)(dst + i) = o;
  }
}

// ---------- weight conversions: Wk/Wv/Wq -> bf16; Ww -> hi/lo bf16 split ----------
__global__ __launch_bounds__(256) void conv_w4(const float* __restrict__ Wk,
    const float* __restrict__ Wv, const float* __restrict__ Wq,
    const float* __restrict__ Ww,
    unsigned short* __restrict__ wkb, unsigned short* __restrict__ wvb,
    unsigned short* __restrict__ wqb,
    unsigned short* __restrict__ wwh, unsigned short* __restrict__ wwl)
{
  int i = (blockIdx.x * 256 + threadIdx.x) * 4;
  if (blockIdx.y == 3) {
    if (i >= 65536) return;
    float4 v = *(const float4*)(Ww + i);
    ushort4 hi, lo;
    hi.x = f2b(v.x); lo.x = f2b(v.x - b2f(hi.x));
    hi.y = f2b(v.y); lo.y = f2b(v.y - b2f(hi.y));
    hi.z = f2b(v.z); lo.z = f2b(v.z - b2f(hi.z));
    hi.w = f2b(v.w); lo.w = f2b(v.w - b2f(hi.w));
    *(ushort4*)(wwh + i) = hi;
    *(ushort4*)(wwl + i) = lo;
    return;
  }
  const float* src = blockIdx.y == 0 ? Wk : (blockIdx.y == 1 ? Wv : Wq);
  unsigned short* dst = blockIdx.y == 0 ? wkb : (blockIdx.y == 1 ? wvb : wqb);
  float4 v = *(const float4*)(src + i);
  ushort4 o; o.x = f2b(v.x); o.y = f2b(v.y); o.z = f2b(v.z); o.w = f2b(v.w);
  *(ushort4*)(dst + i) = o;
}

// ---------- unified 128x128 MFMA GEMM (LDS-staged), K=512 (verified R5-R7) ----------
__global__ __launch_bounds__(256, 2) void gemm128(
    const unsigned short* __restrict__ xbf, const unsigned short* __restrict__ lbf,
    const unsigned short* __restrict__ wkb, const unsigned short* __restrict__ wvb,
    const unsigned short* __restrict__ wqb,
    const float* __restrict__ bk, const float* __restrict__ bv, const float* __restrict__ bq,
    unsigned short* __restrict__ khb, unsigned short* __restrict__ vhb,
    unsigned short* __restrict__ qbuf)
{
  __shared__ unsigned short As[128 * 32];
  __shared__ unsigned short Bs[128 * 32];
  const int id = blockIdx.x;
  const int mode = id < 256 ? 0 : (id < 512 ? 1 : 2);   // 0=K 1=V 2=Q
  const int local = id - (mode == 0 ? 0 : (mode == 1 ? 256 : 512));
  const int rb = local >> 1, cb = local & 1;
  const int m0 = rb * 128, n0 = cb * 128;
  const unsigned short* A = (mode == 2) ? lbf : xbf;
  const unsigned short* W = (mode == 0) ? wkb : (mode == 1 ? wvb : wqb);
  const float* bias = (mode == 0) ? bk : (mode == 1 ? bv : bq);

  const int tid = threadIdx.x, w = tid >> 6, lane = tid & 63;
  const int quad = lane >> 4, l15 = lane & 15;
  const int wr = w >> 1, wc = w & 1;

  const int p0 = tid, p1 = tid + 256;
  const int am0 = p0 >> 2, ak0 = (p0 & 3) * 8;
  const int am1 = p1 >> 2, ak1 = (p1 & 3) * 8;

  f32x4 acc[4][4];
#pragma unroll
  for (int i = 0; i < 4; ++i)
#pragma unroll
    for (int j = 0; j < 4; ++j) acc[i][j] = (f32x4){0.f, 0.f, 0.f, 0.f};

  bf16x8 ar0 = *(const bf16x8*)(A + (size_t)(m0 + am0) * 512 + ak0);
  bf16x8 ar1 = *(const bf16x8*)(A + (size_t)(m0 + am1) * 512 + ak1);
  bf16x8 br0 = *(const bf16x8*)(W + (size_t)(n0 + am0) * 512 + ak0);
  bf16x8 br1 = *(const bf16x8*)(W + (size_t)(n0 + am1) * 512 + ak1);

  for (int kt = 0; kt < 16; ++kt) {
    __syncthreads();
    *(bf16x8*)&As[p0 * 8] = ar0;
    *(bf16x8*)&As[p1 * 8] = ar1;
    *(bf16x8*)&Bs[p0 * 8] = br0;
    *(bf16x8*)&Bs[p1 * 8] = br1;
    if (kt < 15) {
      int k0 = (kt + 1) * 32;
      ar0 = *(const bf16x8*)(A + (size_t)(m0 + am0) * 512 + k0 + ak0);
      ar1 = *(const bf16x8*)(A + (size_t)(m0 + am1) * 512 + k0 + ak1);
      br0 = *(const bf16x8*)(W + (size_t)(n0 + am0) * 512 + k0 + ak0);
      br1 = *(const bf16x8*)(W + (size_t)(n0 + am1) * 512 + k0 + ak1);
    }
    __syncthreads();
    bf16x8 af[4], bf[4];
#pragma unroll
    for (int fr = 0; fr < 4; ++fr)
      af[fr] = *(const bf16x8*)&As[(wr * 64 + fr * 16 + l15) * 32 + quad * 8];
#pragma unroll
    for (int fc = 0; fc < 4; ++fc)
      bf[fc] = *(const bf16x8*)&Bs[(wc * 64 + fc * 16 + l15) * 32 + quad * 8];
#pragma unroll
    for (int fr = 0; fr < 4; ++fr)
#pragma unroll
      for (int fc = 0; fc < 4; ++fc)
        acc[fr][fc] = MFMA16(af[fr], bf[fc], acc[fr][fc], 0, 0, 0);
  }

  float bb[4];
#pragma unroll
  for (int fc = 0; fc < 4; ++fc) bb[fc] = bias[n0 + wc * 64 + fc * 16 + l15];
  unsigned short* dst = (mode == 0) ? khb : (mode == 1 ? vhb : qbuf);
#pragma unroll
  for (int fr = 0; fr < 4; ++fr) {
#pragma unroll
    for (int fc = 0; fc < 4; ++fc) {
      int col = n0 + wc * 64 + fc * 16 + l15;
#pragma unroll
      for (int r = 0; r < 4; ++r) {
        int row = m0 + wr * 64 + fr * 16 + quad * 4 + r;
        unsigned short val = f2b(acc[fr][fc][r] + bb[fc]);
        if (mode == 2) {
          dst[(size_t)row * 256 + col] = val;
        } else {
          int b = row >> 12, n = row & 4095, h = col >> 5, d = col & 31;
          dst[((size_t)(b * 8 + h) * 4096 + n) * 32 + d] = val;
        }
      }
    }
  }
}

// ---------- merged K-stats + V-sums. grid (64, 8) ----------
__global__ __launch_bounds__(256) void kvstats(const unsigned short* __restrict__ khb,
    const unsigned short* __restrict__ vhb,
    float* __restrict__ ksum, float* __restrict__ kss, float* __restrict__ vcs)
{
  const int which = blockIdx.x >> 5, bh = blockIdx.x & 31, seg = blockIdx.y;
  const int t = threadIdx.x, d = t & 31, g = t >> 5;
  __shared__ float rs[256], rss[256];
  if (which == 0) {
    const unsigned short* base = khb + (size_t)bh * 131072 + (size_t)seg * 512 * 32;
    float s = 0.f, ss = 0.f;
    for (int i = 0; i < 64; ++i) {
      float v = b2f(base[(size_t)(g + i * 8) * 32 + d]);
      s += v; ss += v * v;
    }
    rs[t] = s; rss[t] = ss;
    __syncthreads();
    if (t < 32) {
      float a = 0.f, b = 0.f;
      for (int g2 = 0; g2 < 8; ++g2) { a += rs[t + g2 * 32]; b += rss[t + g2 * 32]; }
      atomicAdd(&ksum[bh * 32 + t], a);
      atomicAdd(&kss[bh * 32 + t], b);
    }
  } else {
    const unsigned short* base = vhb + (size_t)bh * 131072 + (size_t)seg * 512 * 32;
    float s = 0.f;
    for (int i = 0; i < 64; ++i) s += b2f(base[(size_t)(g + i * 8) * 32 + d]);
    rs[t] = s;
    __syncthreads();
    if (t < 32) {
      float a = 0.f;
      for (int g2 = 0; g2 < 8; ++g2) a += rs[t + g2 * 32];
      vcs[seg * 1024 + bh * 32 + t] = a;
    }
  }
}

__global__ __launch_bounds__(256) void kfinal(const float* __restrict__ ksum,
    const float* __restrict__ kss, float* __restrict__ krstd)
{
  int i = blockIdx.x * 256 + threadIdx.x;
  float m = ksum[i] * (1.f / 4096.f);
  float var = kss[i] * (1.f / 4096.f) - m * m;
  krstd[i] = rsqrtf(var + 1e-5f);
}

// ---------- pack V head-major -> frag-major, with colmap k-permutation ----------
// colmap(kappa) = (kappa>>2) + 16*(kappa&3): softmax k-order is permuted so the
// attention P-store is vectorizable; must match attn4's ps layout exactly.
__global__ __launch_bounds__(256) void vpack(const unsigned short* __restrict__ vh,
    unsigned short* __restrict__ vfrag)
{
  __shared__ unsigned short vt[256][42];
  const int bh = blockIdx.x >> 4, slab = blockIdx.x & 15;
  const unsigned short* src = vh + ((size_t)bh * 4096 + slab * 256) * 32;
  const int t = threadIdx.x;
#pragma unroll
  for (int i = 0; i < 4; ++i) {
    int p = i * 256 + t;
    int n = p >> 2, piece = p & 3;
    uint4 v = *(const uint4*)(src + (size_t)n * 32 + piece * 8);
    unsigned int* lrow = (unsigned int*)&vt[n][piece * 8];
    lrow[0] = v.x; lrow[1] = v.y; lrow[2] = v.z; lrow[3] = v.w;
  }
  __syncthreads();
#pragma unroll
  for (int i = 0; i < 4; ++i) {
    int op = i * 256 + t;
    int lanep = op & 63, rest = op >> 6;
    int dvt = rest & 1, kh2 = (rest >> 1) & 1, chunkl = rest >> 2;
    int lq = lanep >> 4, ll = lanep & 15;
    unsigned short o[8];
#pragma unroll
    for (int j = 0; j < 8; ++j) {
      int kappa = kh2 * 32 + lq * 8 + j;
      int nloc = (kappa >> 2) + 16 * (kappa & 3);     // colmap
      o[j] = vt[chunkl * 64 + nloc][dvt * 16 + ll];
    }
    size_t dst = ((((size_t)bh * 64 + slab * 4 + chunkl) * 2 + kh2) * 2 + dvt) * 512 + lanep * 8;
    *(bf16x8*)(vfrag + dst) = *(const bf16x8*)o;
  }
}

// ---------- MFMA flash attention v4: 4-way n-split, packed P store, float2 po ----------
// grid (32, 4, 4) = (bh, lsuper, quarter); block 256 (4 waves; wave = 64 l-rows)
__global__ __launch_bounds__(256, 4) void attn4(const unsigned short* __restrict__ qbuf,
    const unsigned short* __restrict__ khb, const unsigned short* __restrict__ vfrag,
    const float* __restrict__ krstd, const float* __restrict__ vcs,
    float* __restrict__ po, float* __restrict__ pd)
{
  const int bh = blockIdx.x, b = bh >> 3, h = bh & 7;
  const int lsuper = blockIdx.y, quarter = blockIdx.z;
  const int tid = threadIdx.x, w = tid >> 6, lane = tid & 63;
  const int quad = lane >> 4, l15 = lane & 15;

  __shared__ unsigned short kb_s[2048];
  __shared__ unsigned short vb_s[2048];
  __shared__ unsigned short ps[4][16][72];   // per-wave, [m-row][kappa], reused per lf

  // Q A-frags with krstd * (1/16) * log2(e) folded in (softmax base-2)
  bf16x8 qa[4];
  {
    float fold[8];
    const float* rp = krstd + bh * 32 + quad * 8;
#pragma unroll
    for (int j = 0; j < 8; ++j) fold[j] = rp[j] * (0.0625f * 1.44269504f);
#pragma unroll
    for (int lf = 0; lf < 4; ++lf) {
      int l = lsuper * 256 + w * 64 + lf * 16 + l15;
      bf16x8 qr = *(const bf16x8*)(qbuf + ((size_t)(b * NL + l)) * 256 + h * 32 + quad * 8);
      const unsigned short* qq = (const unsigned short*)&qr;
      unsigned short tmp[8];
#pragma unroll
      for (int j = 0; j < 8; ++j) tmp[j] = f2b(b2f(qq[j]) * fold[j]);
      qa[lf] = *(const bf16x8*)tmp;
    }
  }

  float drow[4][4];
  f32x4 acc[4][2];
#pragma unroll
  for (int lf = 0; lf < 4; ++lf) {
#pragma unroll
    for (int r = 0; r < 4; ++r) drow[lf][r] = 0.f;
    acc[lf][0] = (f32x4){0.f,0.f,0.f,0.f};
    acc[lf][1] = (f32x4){0.f,0.f,0.f,0.f};
  }

  const unsigned short* kcbase = khb + (size_t)bh * 131072 + (size_t)quarter * 1024 * 32;
  const unsigned short* vcbase = vfrag + (size_t)bh * 131072 + (size_t)quarter * 16 * 2048;

  bf16x8 kreg = *(const bf16x8*)(kcbase + tid * 8);
  bf16x8 vreg = *(const bf16x8*)(vcbase + tid * 8);

  for (int c = 0; c < 16; ++c) {
    __syncthreads();
    *(bf16x8*)&kb_s[tid * 8] = kreg;
    *(bf16x8*)&vb_s[tid * 8] = vreg;
    if (c < 15) {
      kreg = *(const bf16x8*)(kcbase + (c + 1) * 2048 + tid * 8);
      vreg = *(const bf16x8*)(vcbase + (c + 1) * 2048 + tid * 8);
    }
    __syncthreads();

    bf16x8 kb[4];
#pragma unroll
    for (int t = 0; t < 4; ++t)
      kb[t] = *(const bf16x8*)&kb_s[(t * 16 + l15) * 32 + quad * 8];
    bf16x8 vb[4];
#pragma unroll
    for (int i = 0; i < 4; ++i)
      vb[i] = *(const bf16x8*)&vb_s[i * 512 + lane * 8];

    f32x4 z = (f32x4){0.f,0.f,0.f,0.f};
#pragma unroll
    for (int lf = 0; lf < 4; ++lf) {
      f32x4 sv[4];
#pragma unroll
      for (int t = 0; t < 4; ++t) sv[t] = MFMA16(qa[lf], kb[t], z, 0, 0, 0);
#pragma unroll
      for (int r = 0; r < 4; ++r) {
        // e_t = exp2(s) for col l15+16t == kappa 4*l15+t; store packed ushort4 (rtz)
        union { float f; unsigned int u; } e0, e1, e2, e3;
        float x0 = __ocml_native_exp2_f32(sv[0][r]);
        float x1 = __ocml_native_exp2_f32(sv[1][r]);
        float x2 = __ocml_native_exp2_f32(sv[2][r]);
        float x3 = __ocml_native_exp2_f32(sv[3][r]);
        drow[lf][r] += (x0 + x1) + (x2 + x3);
        e0.f = x0 - 1.0f; e1.f = x1 - 1.0f; e2.f = x2 - 1.0f; e3.f = x3 - 1.0f;
        unsigned int lo = (e0.u >> 16) | (e1.u & 0xFFFF0000u);
        unsigned int hi = (e2.u >> 16) | (e3.u & 0xFFFF0000u);
        unsigned int* dst = (unsigned int*)&ps[w][quad * 4 + r][l15 * 4];
        dst[0] = lo; dst[1] = hi;
      }
      asm volatile("s_waitcnt lgkmcnt(0)" ::: "memory");
#pragma unroll
      for (int kh2 = 0; kh2 < 2; ++kh2) {
        bf16x8 pa = *(const bf16x8*)&ps[w][l15][kh2 * 32 + quad * 8];
#pragma unroll
        for (int dvt = 0; dvt < 2; ++dvt)
          acc[lf][dvt] = MFMA16(pa, vb[kh2 * 2 + dvt], acc[lf][dvt], 0, 0, 0);
      }
      asm volatile("s_waitcnt lgkmcnt(0)" ::: "memory");
    }
  }

  // centered-P correction: quarter column-sum of V = two eighth-sums
  const float* vc0 = vcs + (quarter * 2) * 1024 + bh * 32;
  const float* vc1 = vc0 + 1024;
  float cs0 = vc0[l15] + vc1[l15];
  float cs1 = vc0[16 + l15] + vc1[16 + l15];
#pragma unroll
  for (int lf = 0; lf < 4; ++lf)
#pragma unroll
    for (int r = 0; r < 4; ++r) {
      acc[lf][0][r] += cs0;
      acc[lf][1][r] += cs1;
    }

  // write partials; po col layout interleaved: col' = l15*2 + dvt (full-line stores)
  const size_t PDo = (size_t)quarter * 32768 + (size_t)bh * 1024;
#pragma unroll
  for (int lf = 0; lf < 4; ++lf) {
#pragma unroll
    for (int r = 0; r < 4; ++r) {
      float sv = drow[lf][r];
      sv += __shfl_xor(sv, 1, 16);
      sv += __shfl_xor(sv, 2, 16);
      sv += __shfl_xor(sv, 4, 16);
      sv += __shfl_xor(sv, 8, 16);
      int l = lsuper * 256 + w * 64 + lf * 16 + quad * 4 + r;
      float2 val; val.x = acc[lf][0][r]; val.y = acc[lf][1][r];
      *(float2*)(po + (PDo + l) * 32 + l15 * 2) = val;
      if (l15 == 0) pd[PDo + l] = sv;
    }
  }
}

// ---------- combine 4 n-quarters -> ao hi/lo bf16 ----------
__global__ __launch_bounds__(256) void combine4(const float* __restrict__ po,
    const float* __restrict__ pd, unsigned short* __restrict__ aoh,
    unsigned short* __restrict__ aol)
{
  int gid = blockIdx.x * 256 + threadIdx.x;
  int dv = gid & 31, l = (gid >> 5) & (NL - 1), h = (gid >> 15) & 7, b = gid >> 18;
  int c = ((dv & 15) << 1) | (dv >> 4);     // inverse of interleaved po layout
  size_t r = ((size_t)(b * 8 + h)) * 1024 + l;
  float d = 0.f, o = 0.f;
#pragma unroll
  for (int q = 0; q < 4; ++q) {
    size_t rr = (size_t)q * 32768 + r;
    d += pd[rr];
    o += po[rr * 32 + c];
  }
  o = o / d;
  unsigned short hi = f2b(o);
  size_t idx = ((size_t)(b * NL) + l) * 256 + h * 32 + dv;
  aoh[idx] = hi;
  aol[idx] = f2b(o - b2f(hi));
}

// ---------- proj GEMM via MFMA hi/lo (3 passes), K=256. grid (64, 2) ----------
__global__ __launch_bounds__(256) void gemm_proj(
    const unsigned short* __restrict__ aoh, const unsigned short* __restrict__ aol,
    const unsigned short* __restrict__ wwh, const unsigned short* __restrict__ wwl,
    const float* __restrict__ bw, float* __restrict__ pj)
{
  __shared__ unsigned short As[64 * 32];
  __shared__ unsigned short Bs[128 * 32];
  const int bm = blockIdx.x * 64, bn = blockIdx.y * 128;
  const int tid = threadIdx.x, w = tid >> 6, lane = tid & 63;
  const int quad = lane >> 4, l15 = lane & 15;
  const int wr = w >> 1, wc = w & 1;
  const int arow = tid >> 2, apiece = (tid & 3) * 8;

  f32x4 acc[2][4];
#pragma unroll
  for (int i = 0; i < 2; ++i)
#pragma unroll
    for (int j = 0; j < 4; ++j) acc[i][j] = (f32x4){0.f, 0.f, 0.f, 0.f};

  for (int pair = 0; pair < 3; ++pair) {
    const unsigned short* A = (pair == 1) ? aol : aoh;
    const unsigned short* Bm = (pair == 2) ? wwl : wwh;
    for (int kt = 0; kt < 8; ++kt) {
      int k0 = kt * 32;
      __syncthreads();
      *(bf16x8*)&As[tid * 8] = *(const bf16x8*)(A + (size_t)(bm + arow) * 256 + k0 + apiece);
#pragma unroll
      for (int it = 0; it < 2; ++it) {
        int p = tid + it * 256;
        int brow = p >> 2, bpiece = (p & 3) * 8;
        *(bf16x8*)&Bs[p * 8] = *(const bf16x8*)(Bm + (size_t)(bn + brow) * 256 + k0 + bpiece);
      }
      __syncthreads();
      bf16x8 af[2], bf[4];
#pragma unroll
      for (int fr = 0; fr < 2; ++fr)
        af[fr] = *(const bf16x8*)&As[(wr * 32 + fr * 16 + l15) * 32 + quad * 8];
#pragma unroll
      for (int fc = 0; fc < 4; ++fc)
        bf[fc] = *(const bf16x8*)&Bs[(wc * 64 + fc * 16 + l15) * 32 + quad * 8];
#pragma unroll
      for (int fr = 0; fr < 2; ++fr)
#pragma unroll
        for (int fc = 0; fc < 4; ++fc)
          acc[fr][fc] = MFMA16(af[fr], bf[fc], acc[fr][fc], 0, 0, 0);
    }
  }

#pragma unroll
  for (int fr = 0; fr < 2; ++fr)
#pragma unroll
    for (int fc = 0; fc < 4; ++fc) {
      int col = bn + wc * 64 + fc * 16 + l15;
      float bb = bw[col];
#pragma unroll
      for (int r = 0; r < 4; ++r) {
        int row = bm + wr * 32 + fr * 16 + quad * 4 + r;
        pj[(size_t)row * 256 + col] = acc[fr][fc][r] + bb;
      }
    }
}

// ---------- proj instance-norm stats. grid (B, 64), 16 rows/block ----------
__global__ __launch_bounds__(256) void stats_kernel(const float* __restrict__ X,
    long batchStride, int rowsPerBlock,
    float* __restrict__ sum, float* __restrict__ sumsq)
{
  const int b = blockIdx.x, c = threadIdx.x;
  const long r0 = (long)blockIdx.y * rowsPerBlock;
  const float* base = X + (long)b * batchStride + r0 * 256 + c;
  float s = 0.f, ss = 0.f;
  for (int r = 0; r < rowsPerBlock; ++r) {
    float v = base[(long)r * 256];
    s += v; ss += v * v;
  }
  atomicAdd(&sum[b * 256 + c], s);
  atomicAdd(&sumsq[b * 256 + c], ss);
}

__global__ __launch_bounds__(256) void finalize_stats(const float* __restrict__ sum,
    const float* __restrict__ sumsq, float invR,
    float* __restrict__ mean, float* __restrict__ rstd)
{
  int i = blockIdx.x * 256 + threadIdx.x;
  float m = sum[i] * invR;
  float v = sumsq[i] * invR - m * m;
  mean[i] = m;
  rstd[i] = rsqrtf(v + 1e-5f);
}

__global__ __launch_bounds__(256) void final_out(const float* __restrict__ proj,
    const float* __restrict__ mean, const float* __restrict__ rstd,
    float* __restrict__ out)
{
  const int b = blockIdx.x, o = threadIdx.x;
  const int l1 = blockIdx.y * 16;
  const float m = mean[b * 256 + o], r = rstd[b * 256 + o];
  for (int i = 0; i < 16; ++i) {
    size_t idx = ((size_t)(b * NL + l1 + i)) * 256 + o;
    out[idx] = (proj[idx] - m) * r;
  }
}

extern "C" void kernel_launch(void* const* d_in, const int* in_sizes, int n_in,
                              void* d_out, int out_size, void* d_ws, size_t ws_size,
                              hipStream_t stream)
{
  const float* l  = (const float*)d_in[0];
  const float* x  = (const float*)d_in[1];
  const float* Wq = (const float*)d_in[2];
  const float* bq = (const float*)d_in[3];
  const float* Wk = (const float*)d_in[4];
  const float* bk = (const float*)d_in[5];
  const float* Wv = (const float*)d_in[6];
  const float* bv = (const float*)d_in[7];
  const float* Ww = (const float*)d_in[8];
  const float* bw = (const float*)d_in[9];
  float* out = (float*)d_out;

  unsigned short* up = (unsigned short*)d_ws;
  unsigned short* xbf   = up;                         // 8,388,608
  unsigned short* lbf   = xbf   + 8388608;            // 2,097,152
  unsigned short* wkb   = lbf   + 2097152;            // 131,072
  unsigned short* wvb   = wkb   + 131072;
  unsigned short* wqb   = wvb   + 131072;
  unsigned short* qbuf  = wqb   + 131072;             // 1,048,576
  unsigned short* khb   = qbuf  + 1048576;            // 4,194,304
  unsigned short* vhb   = khb   + 4194304;
  unsigned short* vfrag = vhb   + 4194304;
  unsigned short* aoh   = vfrag + 4194304;            // 1,048,576
  unsigned short* aol   = aoh   + 1048576;
  unsigned short* wwh   = aol   + 1048576;            // 65,536
  unsigned short* wwl   = wwh   + 65536;
  // ushort total = 26,738,688 -> 53,477,376 bytes
  float* F     = (float*)((char*)d_ws + 53477376);
  float* krstd = F;                                   // 1024
  float* vcs   = krstd + 1024;                        // 8192
  float* po    = vcs + 8192;                          // 4 * 1,048,576
  float* pd    = po + 4194304;                        // 131,072
  float* pj    = pd + 131072;                         // 1,048,576
  float* st    = pj + 1048576;                        // 6144
  float* ksum  = st;          float* kss   = st + 1024;
  float* psum  = st + 2048;   float* psq   = st + 3072;
  float* pmean = st + 4096;   float* prstd = st + 5120;

  hipMemsetAsync(st, 0, 4096 * sizeof(float), stream);

  dim3 blk(256);
  conv_bf16<<<8192, blk, 0, stream>>>(x,  xbf, 8388608);
  conv_bf16<<<2048, blk, 0, stream>>>(l,  lbf, 2097152);
  conv_w4<<<dim3(128, 4), blk, 0, stream>>>(Wk, Wv, Wq, Ww, wkb, wvb, wqb, wwh, wwl);
  gemm128<<<576, blk, 0, stream>>>(xbf, lbf, wkb, wvb, wqb, bk, bv, bq, khb, vhb, qbuf);
  kvstats<<<dim3(64, 8), blk, 0, stream>>>(khb, vhb, ksum, kss, vcs);
  kfinal<<<4, blk, 0, stream>>>(ksum, kss, krstd);
  vpack<<<512, blk, 0, stream>>>(vhb, vfrag);
  attn4<<<dim3(32, 4, 4), blk, 0, stream>>>(qbuf, khb, vfrag, krstd, vcs, po, pd);
  combine4<<<4096, blk, 0, stream>>>(po, pd, aoh, aol);
  gemm_proj<<<dim3(64, 2), blk, 0, stream>>>(aoh, aol, wwh, wwl, bw, pj);
  stats_kernel<<<dim3(4, 64), blk, 0, stream>>>(pj, (long)NL * 256, 16, psum, psq);
  finalize_stats<<<4, blk, 0, stream>>>(psum, psq, 1.0f / NL, pmean, prstd);
  final_out<<<dim3(4, 64), blk, 0, stream>>>(pj, pmean, prstd, out);
}

// Round 9
// 204.309 us; speedup vs baseline: 1.0959x; 1.0701x over previous
//
#include <hip/hip_runtime.h>

constexpr int Bn = 4, NL = 1024, HWn = 4096, NH = 8;

typedef __attribute__((ext_vector_type(8))) short bf16x8;
typedef __attribute__((ext_vector_type(4))) float f32x4;
#define MFMA16 __builtin_amdgcn_mfma_f32_16x16x32_bf16

extern "C" __device__ float __ocml_native_exp2_f32(float);

__device__ __forceinline__ float b2f(unsigned short u) {
  union { unsigned int i; float f; } x; x.i = ((unsigned int)u) << 16; return x.f;
}
__device__ __forceinline__ unsigned short f2b(float f) {
  union { float f; unsigned int i; } x; x.f = f;
  unsigned int r = x.i + 0x7fffu + ((x.i >> 16) & 1u);   // RNE
  return (unsigned short)(r >> 16);
}

// ---------- f32 -> bf16 ----------
__global__ __launch_bounds__(256) void conv_bf16(const float* __restrict__ src,
    unsigned short* __restrict__ dst, int n)
{
  int i = (blockIdx.x * 256 + threadIdx.x) * 4;
  if (i < n) {
    float4 v = *(const float4*)(src + i);
    ushort4 o; o.x = f2b(v.x); o.y = f2b(v.y); o.z = f2b(v.z); o.w = f2b(v.w);
    *(ushort4*)(dst + i) = o;
  }
}

// ---------- weight conversions: Wk/Wv/Wq -> bf16; Ww -> hi/lo bf16 split ----------
__global__ __launch_bounds__(256) void conv_w4(const float* __restrict__ Wk,
    const float* __restrict__ Wv, const float* __restrict__ Wq,
    const float* __restrict__ Ww,
    unsigned short* __restrict__ wkb, unsigned short* __restrict__ wvb,
    unsigned short* __restrict__ wqb,
    unsigned short* __restrict__ wwh, unsigned short* __restrict__ wwl)
{
  int i = (blockIdx.x * 256 + threadIdx.x) * 4;
  if (blockIdx.y == 3) {
    if (i >= 65536) return;
    float4 v = *(const float4*)(Ww + i);
    ushort4 hi, lo;
    hi.x = f2b(v.x); lo.x = f2b(v.x - b2f(hi.x));
    hi.y = f2b(v.y); lo.y = f2b(v.y - b2f(hi.y));
    hi.z = f2b(v.z); lo.z = f2b(v.z - b2f(hi.z));
    hi.w = f2b(v.w); lo.w = f2b(v.w - b2f(hi.w));
    *(ushort4*)(wwh + i) = hi;
    *(ushort4*)(wwl + i) = lo;
    return;
  }
  const float* src = blockIdx.y == 0 ? Wk : (blockIdx.y == 1 ? Wv : Wq);
  unsigned short* dst = blockIdx.y == 0 ? wkb : (blockIdx.y == 1 ? wvb : wqb);
  float4 v = *(const float4*)(src + i);
  ushort4 o; o.x = f2b(v.x); o.y = f2b(v.y); o.z = f2b(v.z); o.w = f2b(v.w);
  *(ushort4*)(dst + i) = o;
}

// ---------- unified 128x128 MFMA GEMM, K=512, double-buffered LDS ----------
__global__ __launch_bounds__(256, 2) void gemm128(
    const unsigned short* __restrict__ xbf, const unsigned short* __restrict__ lbf,
    const unsigned short* __restrict__ wkb, const unsigned short* __restrict__ wvb,
    const unsigned short* __restrict__ wqb,
    const float* __restrict__ bk, const float* __restrict__ bv, const float* __restrict__ bq,
    unsigned short* __restrict__ khb, unsigned short* __restrict__ vhb,
    unsigned short* __restrict__ qbuf)
{
  __shared__ unsigned short As[2][128 * 32];
  __shared__ unsigned short Bs[2][128 * 32];
  const int id = blockIdx.x;
  const int mode = id < 256 ? 0 : (id < 512 ? 1 : 2);   // 0=K 1=V 2=Q
  const int local = id - (mode == 0 ? 0 : (mode == 1 ? 256 : 512));
  const int rb = local >> 1, cb = local & 1;
  const int m0 = rb * 128, n0 = cb * 128;
  const unsigned short* A = (mode == 2) ? lbf : xbf;
  const unsigned short* W = (mode == 0) ? wkb : (mode == 1 ? wvb : wqb);
  const float* bias = (mode == 0) ? bk : (mode == 1 ? bv : bq);

  const int tid = threadIdx.x, w = tid >> 6, lane = tid & 63;
  const int quad = lane >> 4, l15 = lane & 15;
  const int wr = w >> 1, wc = w & 1;

  const int p0 = tid, p1 = tid + 256;
  const int am0 = p0 >> 2, ak0 = (p0 & 3) * 8;
  const int am1 = p1 >> 2, ak1 = (p1 & 3) * 8;

  f32x4 acc[4][4];
#pragma unroll
  for (int i = 0; i < 4; ++i)
#pragma unroll
    for (int j = 0; j < 4; ++j) acc[i][j] = (f32x4){0.f, 0.f, 0.f, 0.f};

  bf16x8 ar0 = *(const bf16x8*)(A + (size_t)(m0 + am0) * 512 + ak0);
  bf16x8 ar1 = *(const bf16x8*)(A + (size_t)(m0 + am1) * 512 + ak1);
  bf16x8 br0 = *(const bf16x8*)(W + (size_t)(n0 + am0) * 512 + ak0);
  bf16x8 br1 = *(const bf16x8*)(W + (size_t)(n0 + am1) * 512 + ak1);

  for (int kt = 0; kt < 16; ++kt) {
    const int cur = kt & 1;
    *(bf16x8*)&As[cur][p0 * 8] = ar0;
    *(bf16x8*)&As[cur][p1 * 8] = ar1;
    *(bf16x8*)&Bs[cur][p0 * 8] = br0;
    *(bf16x8*)&Bs[cur][p1 * 8] = br1;
    __syncthreads();
    if (kt < 15) {
      int k0 = (kt + 1) * 32;
      ar0 = *(const bf16x8*)(A + (size_t)(m0 + am0) * 512 + k0 + ak0);
      ar1 = *(const bf16x8*)(A + (size_t)(m0 + am1) * 512 + k0 + ak1);
      br0 = *(const bf16x8*)(W + (size_t)(n0 + am0) * 512 + k0 + ak0);
      br1 = *(const bf16x8*)(W + (size_t)(n0 + am1) * 512 + k0 + ak1);
    }
    bf16x8 af[4], bf[4];
#pragma unroll
    for (int fr = 0; fr < 4; ++fr)
      af[fr] = *(const bf16x8*)&As[cur][(wr * 64 + fr * 16 + l15) * 32 + quad * 8];
#pragma unroll
    for (int fc = 0; fc < 4; ++fc)
      bf[fc] = *(const bf16x8*)&Bs[cur][(wc * 64 + fc * 16 + l15) * 32 + quad * 8];
#pragma unroll
    for (int fr = 0; fr < 4; ++fr)
#pragma unroll
      for (int fc = 0; fc < 4; ++fc)
        acc[fr][fc] = MFMA16(af[fr], bf[fc], acc[fr][fc], 0, 0, 0);
  }

  float bb[4];
#pragma unroll
  for (int fc = 0; fc < 4; ++fc) bb[fc] = bias[n0 + wc * 64 + fc * 16 + l15];
  unsigned short* dst = (mode == 0) ? khb : (mode == 1 ? vhb : qbuf);
#pragma unroll
  for (int fr = 0; fr < 4; ++fr) {
#pragma unroll
    for (int fc = 0; fc < 4; ++fc) {
      int col = n0 + wc * 64 + fc * 16 + l15;
#pragma unroll
      for (int r = 0; r < 4; ++r) {
        int row = m0 + wr * 64 + fr * 16 + quad * 4 + r;
        unsigned short val = f2b(acc[fr][fc][r] + bb[fc]);
        if (mode == 2) {
          dst[(size_t)row * 256 + col] = val;
        } else {
          int b = row >> 12, n = row & 4095, h = col >> 5, d = col & 31;
          dst[((size_t)(b * 8 + h) * 4096 + n) * 32 + d] = val;
        }
      }
    }
  }
}

// ---------- merged K-stats + V-sums. grid (64, 8) ----------
__global__ __launch_bounds__(256) void kvstats(const unsigned short* __restrict__ khb,
    const unsigned short* __restrict__ vhb,
    float* __restrict__ ksum, float* __restrict__ kss, float* __restrict__ vcs)
{
  const int which = blockIdx.x >> 5, bh = blockIdx.x & 31, seg = blockIdx.y;
  const int t = threadIdx.x, d = t & 31, g = t >> 5;
  __shared__ float rs[256], rss[256];
  if (which == 0) {
    const unsigned short* base = khb + (size_t)bh * 131072 + (size_t)seg * 512 * 32;
    float s = 0.f, ss = 0.f;
    for (int i = 0; i < 64; ++i) {
      float v = b2f(base[(size_t)(g + i * 8) * 32 + d]);
      s += v; ss += v * v;
    }
    rs[t] = s; rss[t] = ss;
    __syncthreads();
    if (t < 32) {
      float a = 0.f, b = 0.f;
      for (int g2 = 0; g2 < 8; ++g2) { a += rs[t + g2 * 32]; b += rss[t + g2 * 32]; }
      atomicAdd(&ksum[bh * 32 + t], a);
      atomicAdd(&kss[bh * 32 + t], b);
    }
  } else {
    const unsigned short* base = vhb + (size_t)bh * 131072 + (size_t)seg * 512 * 32;
    float s = 0.f;
    for (int i = 0; i < 64; ++i) s += b2f(base[(size_t)(g + i * 8) * 32 + d]);
    rs[t] = s;
    __syncthreads();
    if (t < 32) {
      float a = 0.f;
      for (int g2 = 0; g2 < 8; ++g2) a += rs[t + g2 * 32];
      vcs[seg * 1024 + bh * 32 + t] = a;
    }
  }
}

__global__ __launch_bounds__(256) void kfinal(const float* __restrict__ ksum,
    const float* __restrict__ kss, float* __restrict__ krstd)
{
  int i = blockIdx.x * 256 + threadIdx.x;
  float m = ksum[i] * (1.f / 4096.f);
  float var = kss[i] * (1.f / 4096.f) - m * m;
  krstd[i] = rsqrtf(var + 1e-5f);
}

// ---------- pack V head-major -> frag-major, with colmap k-permutation ----------
// colmap(kappa) = (kappa>>2) + 16*(kappa&3) — must match attn5's packed P store.
__global__ __launch_bounds__(256) void vpack(const unsigned short* __restrict__ vh,
    unsigned short* __restrict__ vfrag)
{
  __shared__ unsigned short vt[256][42];
  const int bh = blockIdx.x >> 4, slab = blockIdx.x & 15;
  const unsigned short* src = vh + ((size_t)bh * 4096 + slab * 256) * 32;
  const int t = threadIdx.x;
#pragma unroll
  for (int i = 0; i < 4; ++i) {
    int p = i * 256 + t;
    int n = p >> 2, piece = p & 3;
    uint4 v = *(const uint4*)(src + (size_t)n * 32 + piece * 8);
    unsigned int* lrow = (unsigned int*)&vt[n][piece * 8];
    lrow[0] = v.x; lrow[1] = v.y; lrow[2] = v.z; lrow[3] = v.w;
  }
  __syncthreads();
#pragma unroll
  for (int i = 0; i < 4; ++i) {
    int op = i * 256 + t;
    int lanep = op & 63, rest = op >> 6;
    int dvt = rest & 1, kh2 = (rest >> 1) & 1, chunkl = rest >> 2;
    int lq = lanep >> 4, ll = lanep & 15;
    unsigned short o[8];
#pragma unroll
    for (int j = 0; j < 8; ++j) {
      int kappa = kh2 * 32 + lq * 8 + j;
      int nloc = (kappa >> 2) + 16 * (kappa & 3);     // colmap
      o[j] = vt[chunkl * 64 + nloc][dvt * 16 + ll];
    }
    size_t dst = ((((size_t)bh * 64 + slab * 4 + chunkl) * 2 + kh2) * 2 + dvt) * 512 + lanep * 8;
    *(bf16x8*)(vfrag + dst) = *(const bf16x8*)o;
  }
}

// ---------- MFMA flash attention v5: KV double-buffer (1 barrier/chunk),
// per-lf ps buffers (no post-PV drain, lf pipelining), packed P store, float2 po ----------
// grid (32, 4, 4) = (bh, lsuper, quarter); block 256 (4 waves; wave = 64 l-rows)
__global__ __launch_bounds__(256, 2) void attn5(const unsigned short* __restrict__ qbuf,
    const unsigned short* __restrict__ khb, const unsigned short* __restrict__ vfrag,
    const float* __restrict__ krstd, const float* __restrict__ vcs,
    float* __restrict__ po, float* __restrict__ pd)
{
  const int bh = blockIdx.x, b = bh >> 3, h = bh & 7;
  const int lsuper = blockIdx.y, quarter = blockIdx.z;
  const int tid = threadIdx.x, w = tid >> 6, lane = tid & 63;
  const int quad = lane >> 4, l15 = lane & 15;

  __shared__ unsigned short kb_s[2][2048];
  __shared__ unsigned short vb_s[2][2048];
  __shared__ unsigned short ps[4][4][16][72];   // [wave][lf][row][kappa] - no reuse hazard

  // Q A-frags with krstd * (1/16) * log2(e) folded in (softmax base-2)
  bf16x8 qa[4];
  {
    float fold[8];
    const float* rp = krstd + bh * 32 + quad * 8;
#pragma unroll
    for (int j = 0; j < 8; ++j) fold[j] = rp[j] * (0.0625f * 1.44269504f);
#pragma unroll
    for (int lf = 0; lf < 4; ++lf) {
      int l = lsuper * 256 + w * 64 + lf * 16 + l15;
      bf16x8 qr = *(const bf16x8*)(qbuf + ((size_t)(b * NL + l)) * 256 + h * 32 + quad * 8);
      const unsigned short* qq = (const unsigned short*)&qr;
      unsigned short tmp[8];
#pragma unroll
      for (int j = 0; j < 8; ++j) tmp[j] = f2b(b2f(qq[j]) * fold[j]);
      qa[lf] = *(const bf16x8*)tmp;
    }
  }

  float drow[4][4];
  f32x4 acc[4][2];
#pragma unroll
  for (int lf = 0; lf < 4; ++lf) {
#pragma unroll
    for (int r = 0; r < 4; ++r) drow[lf][r] = 0.f;
    acc[lf][0] = (f32x4){0.f,0.f,0.f,0.f};
    acc[lf][1] = (f32x4){0.f,0.f,0.f,0.f};
  }

  const unsigned short* kcbase = khb + (size_t)bh * 131072 + (size_t)quarter * 1024 * 32;
  const unsigned short* vcbase = vfrag + (size_t)bh * 131072 + (size_t)quarter * 16 * 2048;

  bf16x8 kreg = *(const bf16x8*)(kcbase + tid * 8);
  bf16x8 vreg = *(const bf16x8*)(vcbase + tid * 8);

  for (int c = 0; c < 16; ++c) {
    const int cur = c & 1;
    // stage chunk c (regs -> LDS buf[cur]); chunk c-1 readers used buf[cur^1] - safe
    *(bf16x8*)&kb_s[cur][tid * 8] = kreg;
    *(bf16x8*)&vb_s[cur][tid * 8] = vreg;
    __syncthreads();                      // single barrier per chunk
    if (c < 15) {                         // prefetch c+1: lands during this chunk's compute
      kreg = *(const bf16x8*)(kcbase + (c + 1) * 2048 + tid * 8);
      vreg = *(const bf16x8*)(vcbase + (c + 1) * 2048 + tid * 8);
    }

    bf16x8 kb[4];
#pragma unroll
    for (int t = 0; t < 4; ++t)
      kb[t] = *(const bf16x8*)&kb_s[cur][(t * 16 + l15) * 32 + quad * 8];
    bf16x8 vb[4];
#pragma unroll
    for (int i = 0; i < 4; ++i)
      vb[i] = *(const bf16x8*)&vb_s[cur][i * 512 + lane * 8];

    f32x4 z = (f32x4){0.f,0.f,0.f,0.f};
#pragma unroll
    for (int lf = 0; lf < 4; ++lf) {
      f32x4 sv[4];
#pragma unroll
      for (int t = 0; t < 4; ++t) sv[t] = MFMA16(qa[lf], kb[t], z, 0, 0, 0);
#pragma unroll
      for (int r = 0; r < 4; ++r) {
        // e_t for col l15+16t == kappa 4*l15+t; packed ushort4 store (rtz)
        union { float f; unsigned int u; } e0, e1, e2, e3;
        float x0 = __ocml_native_exp2_f32(sv[0][r]);
        float x1 = __ocml_native_exp2_f32(sv[1][r]);
        float x2 = __ocml_native_exp2_f32(sv[2][r]);
        float x3 = __ocml_native_exp2_f32(sv[3][r]);
        drow[lf][r] += (x0 + x1) + (x2 + x3);
        e0.f = x0 - 1.0f; e1.f = x1 - 1.0f; e2.f = x2 - 1.0f; e3.f = x3 - 1.0f;
        unsigned int lo = (e0.u >> 16) | (e1.u & 0xFFFF0000u);
        unsigned int hi = (e2.u >> 16) | (e3.u & 0xFFFF0000u);
        unsigned int* dst = (unsigned int*)&ps[w][lf][quad * 4 + r][l15 * 4];
        dst[0] = lo; dst[1] = hi;
      }
      asm volatile("s_waitcnt lgkmcnt(0)" ::: "memory");   // this wave's P stores visible
#pragma unroll
      for (int kh2 = 0; kh2 < 2; ++kh2) {
        bf16x8 pa = *(const bf16x8*)&ps[w][lf][l15][kh2 * 32 + quad * 8];
#pragma unroll
        for (int dvt = 0; dvt < 2; ++dvt)
          acc[lf][dvt] = MFMA16(pa, vb[kh2 * 2 + dvt], acc[lf][dvt], 0, 0, 0);
      }
      // no trailing drain: next lf uses its own ps buffer
    }
  }

  // centered-P correction: quarter column-sum of V = two eighth-sums
  const float* vc0 = vcs + (quarter * 2) * 1024 + bh * 32;
  const float* vc1 = vc0 + 1024;
  float cs0 = vc0[l15] + vc1[l15];
  float cs1 = vc0[16 + l15] + vc1[16 + l15];
#pragma unroll
  for (int lf = 0; lf < 4; ++lf)
#pragma unroll
    for (int r = 0; r < 4; ++r) {
      acc[lf][0][r] += cs0;
      acc[lf][1][r] += cs1;
    }

  // write partials; po col layout interleaved: col' = l15*2 + dvt (full-line stores)
  const size_t PDo = (size_t)quarter * 32768 + (size_t)bh * 1024;
#pragma unroll
  for (int lf = 0; lf < 4; ++lf) {
#pragma unroll
    for (int r = 0; r < 4; ++r) {
      float sv = drow[lf][r];
      sv += __shfl_xor(sv, 1, 16);
      sv += __shfl_xor(sv, 2, 16);
      sv += __shfl_xor(sv, 4, 16);
      sv += __shfl_xor(sv, 8, 16);
      int l = lsuper * 256 + w * 64 + lf * 16 + quad * 4 + r;
      float2 val; val.x = acc[lf][0][r]; val.y = acc[lf][1][r];
      *(float2*)(po + (PDo + l) * 32 + l15 * 2) = val;
      if (l15 == 0) pd[PDo + l] = sv;
    }
  }
}

// ---------- combine 4 n-quarters -> ao hi/lo bf16 ----------
__global__ __launch_bounds__(256) void combine4(const float* __restrict__ po,
    const float* __restrict__ pd, unsigned short* __restrict__ aoh,
    unsigned short* __restrict__ aol)
{
  int gid = blockIdx.x * 256 + threadIdx.x;
  int dv = gid & 31, l = (gid >> 5) & (NL - 1), h = (gid >> 15) & 7, b = gid >> 18;
  int c = ((dv & 15) << 1) | (dv >> 4);     // inverse of interleaved po layout
  size_t r = ((size_t)(b * 8 + h)) * 1024 + l;
  float d = 0.f, o = 0.f;
#pragma unroll
  for (int q = 0; q < 4; ++q) {
    size_t rr = (size_t)q * 32768 + r;
    d += pd[rr];
    o += po[rr * 32 + c];
  }
  o = o / d;
  unsigned short hi = f2b(o);
  size_t idx = ((size_t)(b * NL) + l) * 256 + h * 32 + dv;
  aoh[idx] = hi;
  aol[idx] = f2b(o - b2f(hi));
}

// ---------- proj GEMM via MFMA hi/lo (3 passes), K=256. grid (64, 2) ----------
__global__ __launch_bounds__(256) void gemm_proj(
    const unsigned short* __restrict__ aoh, const unsigned short* __restrict__ aol,
    const unsigned short* __restrict__ wwh, const unsigned short* __restrict__ wwl,
    const float* __restrict__ bw, float* __restrict__ pj)
{
  __shared__ unsigned short As[64 * 32];
  __shared__ unsigned short Bs[128 * 32];
  const int bm = blockIdx.x * 64, bn = blockIdx.y * 128;
  const int tid = threadIdx.x, w = tid >> 6, lane = tid & 63;
  const int quad = lane >> 4, l15 = lane & 15;
  const int wr = w >> 1, wc = w & 1;
  const int arow = tid >> 2, apiece = (tid & 3) * 8;

  f32x4 acc[2][4];
#pragma unroll
  for (int i = 0; i < 2; ++i)
#pragma unroll
    for (int j = 0; j < 4; ++j) acc[i][j] = (f32x4){0.f, 0.f, 0.f, 0.f};

  for (int pair = 0; pair < 3; ++pair) {
    const unsigned short* A = (pair == 1) ? aol : aoh;
    const unsigned short* Bm = (pair == 2) ? wwl : wwh;
    for (int kt = 0; kt < 8; ++kt) {
      int k0 = kt * 32;
      __syncthreads();
      *(bf16x8*)&As[tid * 8] = *(const bf16x8*)(A + (size_t)(bm + arow) * 256 + k0 + apiece);
#pragma unroll
      for (int it = 0; it < 2; ++it) {
        int p = tid + it * 256;
        int brow = p >> 2, bpiece = (p & 3) * 8;
        *(bf16x8*)&Bs[p * 8] = *(const bf16x8*)(Bm + (size_t)(bn + brow) * 256 + k0 + bpiece);
      }
      __syncthreads();
      bf16x8 af[2], bf[4];
#pragma unroll
      for (int fr = 0; fr < 2; ++fr)
        af[fr] = *(const bf16x8*)&As[(wr * 32 + fr * 16 + l15) * 32 + quad * 8];
#pragma unroll
      for (int fc = 0; fc < 4; ++fc)
        bf[fc] = *(const bf16x8*)&Bs[(wc * 64 + fc * 16 + l15) * 32 + quad * 8];
#pragma unroll
      for (int fr = 0; fr < 2; ++fr)
#pragma unroll
        for (int fc = 0; fc < 4; ++fc)
          acc[fr][fc] = MFMA16(af[fr], bf[fc], acc[fr][fc], 0, 0, 0);
    }
  }

#pragma unroll
  for (int fr = 0; fr < 2; ++fr)
#pragma unroll
    for (int fc = 0; fc < 4; ++fc) {
      int col = bn + wc * 64 + fc * 16 + l15;
      float bb = bw[col];
#pragma unroll
      for (int r = 0; r < 4; ++r) {
        int row = bm + wr * 32 + fr * 16 + quad * 4 + r;
        pj[(size_t)row * 256 + col] = acc[fr][fc][r] + bb;
      }
    }
}

// ---------- proj instance-norm stats. grid (B, 64), 16 rows/block ----------
__global__ __launch_bounds__(256) void stats_kernel(const float* __restrict__ X,
    long batchStride, int rowsPerBlock,
    float* __restrict__ sum, float* __restrict__ sumsq)
{
  const int b = blockIdx.x, c = threadIdx.x;
  const long r0 = (long)blockIdx.y * rowsPerBlock;
  const float* base = X + (long)b * batchStride + r0 * 256 + c;
  float s = 0.f, ss = 0.f;
  for (int r = 0; r < rowsPerBlock; ++r) {
    float v = base[(long)r * 256];
    s += v; ss += v * v;
  }
  atomicAdd(&sum[b * 256 + c], s);
  atomicAdd(&sumsq[b * 256 + c], ss);
}

__global__ __launch_bounds__(256) void finalize_stats(const float* __restrict__ sum,
    const float* __restrict__ sumsq, float invR,
    float* __restrict__ mean, float* __restrict__ rstd)
{
  int i = blockIdx.x * 256 + threadIdx.x;
  float m = sum[i] * invR;
  float v = sumsq[i] * invR - m * m;
  mean[i] = m;
  rstd[i] = rsqrtf(v + 1e-5f);
}

__global__ __launch_bounds__(256) void final_out(const float* __restrict__ proj,
    const float* __restrict__ mean, const float* __restrict__ rstd,
    float* __restrict__ out)
{
  const int b = blockIdx.x, o = threadIdx.x;
  const int l1 = blockIdx.y * 16;
  const float m = mean[b * 256 + o], r = rstd[b * 256 + o];
  for (int i = 0; i < 16; ++i) {
    size_t idx = ((size_t)(b * NL + l1 + i)) * 256 + o;
    out[idx] = (proj[idx] - m) * r;
  }
}

extern "C" void kernel_launch(void* const* d_in, const int* in_sizes, int n_in,
                              void* d_out, int out_size, void* d_ws, size_t ws_size,
                              hipStream_t stream)
{
  const float* l  = (const float*)d_in[0];
  const float* x  = (const float*)d_in[1];
  const float* Wq = (const float*)d_in[2];
  const float* bq = (const float*)d_in[3];
  const float* Wk = (const float*)d_in[4];
  const float* bk = (const float*)d_in[5];
  const float* Wv = (const float*)d_in[6];
  const float* bv = (const float*)d_in[7];
  const float* Ww = (const float*)d_in[8];
  const float* bw = (const float*)d_in[9];
  float* out = (float*)d_out;

  unsigned short* up = (unsigned short*)d_ws;
  unsigned short* xbf   = up;                         // 8,388,608
  unsigned short* lbf   = xbf   + 8388608;            // 2,097,152
  unsigned short* wkb   = lbf   + 2097152;            // 131,072
  unsigned short* wvb   = wkb   + 131072;
  unsigned short* wqb   = wvb   + 131072;
  unsigned short* qbuf  = wqb   + 131072;             // 1,048,576
  unsigned short* khb   = qbuf  + 1048576;            // 4,194,304
  unsigned short* vhb   = khb   + 4194304;
  unsigned short* vfrag = vhb   + 4194304;
  unsigned short* aoh   = vfrag + 4194304;            // 1,048,576
  unsigned short* aol   = aoh   + 1048576;
  unsigned short* wwh   = aol   + 1048576;            // 65,536
  unsigned short* wwl   = wwh   + 65536;
  // ushort total = 26,738,688 -> 53,477,376 bytes
  float* F     = (float*)((char*)d_ws + 53477376);
  float* krstd = F;                                   // 1024
  float* vcs   = krstd + 1024;                        // 8192
  float* po    = vcs + 8192;                          // 4 * 1,048,576
  float* pd    = po + 4194304;                        // 131,072
  float* pj    = pd + 131072;                         // 1,048,576
  float* st    = pj + 1048576;                        // 6144
  float* ksum  = st;          float* kss   = st + 1024;
  float* psum  = st + 2048;   float* psq   = st + 3072;
  float* pmean = st + 4096;   float* prstd = st + 5120;

  hipMemsetAsync(st, 0, 4096 * sizeof(float), stream);

  dim3 blk(256);
  conv_bf16<<<8192, blk, 0, stream>>>(x,  xbf, 8388608);
  conv_bf16<<<2048, blk, 0, stream>>>(l,  lbf, 2097152);
  conv_w4<<<dim3(128, 4), blk, 0, stream>>>(Wk, Wv, Wq, Ww, wkb, wvb, wqb, wwh, wwl);
  gemm128<<<576, blk, 0, stream>>>(xbf, lbf, wkb, wvb, wqb, bk, bv, bq, khb, vhb, qbuf);
  kvstats<<<dim3(64, 8), blk, 0, stream>>>(khb, vhb, ksum, kss, vcs);
  kfinal<<<4, blk, 0, stream>>>(ksum, kss, krstd);
  vpack<<<512, blk, 0, stream>>>(vhb, vfrag);
  attn5<<<dim3(32, 4, 4), blk, 0, stream>>>(qbuf, khb, vfrag, krstd, vcs, po, pd);
  combine4<<<4096, blk, 0, stream>>>(po, pd, aoh, aol);
  gemm_proj<<<dim3(64, 2), blk, 0, stream>>>(aoh, aol, wwh, wwl, bw, pj);
  stats_kernel<<<dim3(4, 64), blk, 0, stream>>>(pj, (long)NL * 256, 16, psum, psq);
  finalize_stats<<<4, blk, 0, stream>>>(psum, psq, 1.0f / NL, pmean, prstd);
  final_out<<<dim3(4, 64), blk, 0, stream>>>(pj, pmean, prstd, out);
}

// Round 10
// 203.717 us; speedup vs baseline: 1.0991x; 1.0029x over previous
//
#include <hip/hip_runtime.h>

constexpr int Bn = 4, NL = 1024, HWn = 4096, NH = 8;

typedef __attribute__((ext_vector_type(8))) short bf16x8;
typedef __attribute__((ext_vector_type(4))) float f32x4;
#define MFMA16 __builtin_amdgcn_mfma_f32_16x16x32_bf16

extern "C" __device__ float __ocml_native_exp2_f32(float);

__device__ __forceinline__ float b2f(unsigned short u) {
  union { unsigned int i; float f; } x; x.i = ((unsigned int)u) << 16; return x.f;
}
__device__ __forceinline__ unsigned short f2b(float f) {
  union { float f; unsigned int i; } x; x.f = f;
  unsigned int r = x.i + 0x7fffu + ((x.i >> 16) & 1u);   // RNE
  return (unsigned short)(r >> 16);
}

// async global->LDS DMA, 16B per lane; LDS dst = readfirstlane(l) + lane*16
__device__ __forceinline__ void async_load16(const unsigned short* g, unsigned short* l) {
  __builtin_amdgcn_global_load_lds(
      (const __attribute__((address_space(1))) unsigned int*)g,
      (__attribute__((address_space(3))) unsigned int*)l, 16, 0, 0);
}

// ---------- f32 -> bf16 ----------
__global__ __launch_bounds__(256) void conv_bf16(const float* __restrict__ src,
    unsigned short* __restrict__ dst, int n)
{
  int i = (blockIdx.x * 256 + threadIdx.x) * 4;
  if (i < n) {
    float4 v = *(const float4*)(src + i);
    ushort4 o; o.x = f2b(v.x); o.y = f2b(v.y); o.z = f2b(v.z); o.w = f2b(v.w);
    *(ushort4*)(dst + i) = o;
  }
}

// ---------- weight conversions: Wk/Wv/Wq -> bf16; Ww -> hi/lo bf16 split ----------
__global__ __launch_bounds__(256) void conv_w4(const float* __restrict__ Wk,
    const float* __restrict__ Wv, const float* __restrict__ Wq,
    const float* __restrict__ Ww,
    unsigned short* __restrict__ wkb, unsigned short* __restrict__ wvb,
    unsigned short* __restrict__ wqb,
    unsigned short* __restrict__ wwh, unsigned short* __restrict__ wwl)
{
  int i = (blockIdx.x * 256 + threadIdx.x) * 4;
  if (blockIdx.y == 3) {
    if (i >= 65536) return;
    float4 v = *(const float4*)(Ww + i);
    ushort4 hi, lo;
    hi.x = f2b(v.x); lo.x = f2b(v.x - b2f(hi.x));
    hi.y = f2b(v.y); lo.y = f2b(v.y - b2f(hi.y));
    hi.z = f2b(v.z); lo.z = f2b(v.z - b2f(hi.z));
    hi.w = f2b(v.w); lo.w = f2b(v.w - b2f(hi.w));
    *(ushort4*)(wwh + i) = hi;
    *(ushort4*)(wwl + i) = lo;
    return;
  }
  const float* src = blockIdx.y == 0 ? Wk : (blockIdx.y == 1 ? Wv : Wq);
  unsigned short* dst = blockIdx.y == 0 ? wkb : (blockIdx.y == 1 ? wvb : wqb);
  float4 v = *(const float4*)(src + i);
  ushort4 o; o.x = f2b(v.x); o.y = f2b(v.y); o.z = f2b(v.z); o.w = f2b(v.w);
  *(ushort4*)(dst + i) = o;
}

// ---------- unified 128x128 MFMA GEMM, K=512, dbuf LDS + global_load_lds ----------
__global__ __launch_bounds__(256, 3) void gemm128(
    const unsigned short* __restrict__ xbf, const unsigned short* __restrict__ lbf,
    const unsigned short* __restrict__ wkb, const unsigned short* __restrict__ wvb,
    const unsigned short* __restrict__ wqb,
    const float* __restrict__ bk, const float* __restrict__ bv, const float* __restrict__ bq,
    unsigned short* __restrict__ khb, unsigned short* __restrict__ vhb,
    unsigned short* __restrict__ qbuf)
{
  __shared__ unsigned short As[2][4096];
  __shared__ unsigned short Bs[2][4096];
  const int id = blockIdx.x;
  const int mode = id < 256 ? 0 : (id < 512 ? 1 : 2);   // 0=K 1=V 2=Q
  const int local = id - (mode == 0 ? 0 : (mode == 1 ? 256 : 512));
  const int rb = local >> 1, cb = local & 1;
  const int m0 = rb * 128, n0 = cb * 128;
  const unsigned short* A = (mode == 2) ? lbf : xbf;
  const unsigned short* W = (mode == 0) ? wkb : (mode == 1 ? wvb : wqb);
  const float* bias = (mode == 0) ? bk : (mode == 1 ? bv : bq);

  const int tid = threadIdx.x, w = tid >> 6, lane = tid & 63;
  const int quad = lane >> 4, l15 = lane & 15;
  const int wr = w >> 1, wc = w & 1;

  const int p0 = tid, p1 = tid + 256;
  const int am0 = p0 >> 2, ak0 = (p0 & 3) * 8;
  const int am1 = p1 >> 2, ak1 = (p1 & 3) * 8;

  f32x4 acc[4][4];
#pragma unroll
  for (int i = 0; i < 4; ++i)
#pragma unroll
    for (int j = 0; j < 4; ++j) acc[i][j] = (f32x4){0.f, 0.f, 0.f, 0.f};

  // prologue: async-stage kt=0 into buf 0
  async_load16(A + (size_t)(m0 + am0) * 512 + ak0, &As[0][p0 * 8]);
  async_load16(A + (size_t)(m0 + am1) * 512 + ak1, &As[0][p1 * 8]);
  async_load16(W + (size_t)(n0 + am0) * 512 + ak0, &Bs[0][p0 * 8]);
  async_load16(W + (size_t)(n0 + am1) * 512 + ak1, &Bs[0][p1 * 8]);

  for (int kt = 0; kt < 16; ++kt) {
    const int cur = kt & 1;
    __syncthreads();                       // buf[cur] DMA complete (vmcnt drained)
    if (kt < 15) {                         // prefetch kt+1 into the other buffer
      int k0 = (kt + 1) * 32;
      async_load16(A + (size_t)(m0 + am0) * 512 + k0 + ak0, &As[cur ^ 1][p0 * 8]);
      async_load16(A + (size_t)(m0 + am1) * 512 + k0 + ak1, &As[cur ^ 1][p1 * 8]);
      async_load16(W + (size_t)(n0 + am0) * 512 + k0 + ak0, &Bs[cur ^ 1][p0 * 8]);
      async_load16(W + (size_t)(n0 + am1) * 512 + k0 + ak1, &Bs[cur ^ 1][p1 * 8]);
    }
    bf16x8 af[4], bf[4];
#pragma unroll
    for (int fr = 0; fr < 4; ++fr)
      af[fr] = *(const bf16x8*)&As[cur][(wr * 64 + fr * 16 + l15) * 32 + quad * 8];
#pragma unroll
    for (int fc = 0; fc < 4; ++fc)
      bf[fc] = *(const bf16x8*)&Bs[cur][(wc * 64 + fc * 16 + l15) * 32 + quad * 8];
#pragma unroll
    for (int fr = 0; fr < 4; ++fr)
#pragma unroll
      for (int fc = 0; fc < 4; ++fc)
        acc[fr][fc] = MFMA16(af[fr], bf[fc], acc[fr][fc], 0, 0, 0);
  }

  float bb[4];
#pragma unroll
  for (int fc = 0; fc < 4; ++fc) bb[fc] = bias[n0 + wc * 64 + fc * 16 + l15];
  unsigned short* dst = (mode == 0) ? khb : (mode == 1 ? vhb : qbuf);
#pragma unroll
  for (int fr = 0; fr < 4; ++fr) {
#pragma unroll
    for (int fc = 0; fc < 4; ++fc) {
      int col = n0 + wc * 64 + fc * 16 + l15;
#pragma unroll
      for (int r = 0; r < 4; ++r) {
        int row = m0 + wr * 64 + fr * 16 + quad * 4 + r;
        unsigned short val = f2b(acc[fr][fc][r] + bb[fc]);
        if (mode == 2) {
          dst[(size_t)row * 256 + col] = val;
        } else {
          int b = row >> 12, n = row & 4095, h = col >> 5, d = col & 31;
          dst[((size_t)(b * 8 + h) * 4096 + n) * 32 + d] = val;
        }
      }
    }
  }
}

// ---------- merged K-stats + V-sums. grid (64, 8) ----------
__global__ __launch_bounds__(256) void kvstats(const unsigned short* __restrict__ khb,
    const unsigned short* __restrict__ vhb,
    float* __restrict__ ksum, float* __restrict__ kss, float* __restrict__ vcs)
{
  const int which = blockIdx.x >> 5, bh = blockIdx.x & 31, seg = blockIdx.y;
  const int t = threadIdx.x, d = t & 31, g = t >> 5;
  __shared__ float rs[256], rss[256];
  if (which == 0) {
    const unsigned short* base = khb + (size_t)bh * 131072 + (size_t)seg * 512 * 32;
    float s = 0.f, ss = 0.f;
    for (int i = 0; i < 64; ++i) {
      float v = b2f(base[(size_t)(g + i * 8) * 32 + d]);
      s += v; ss += v * v;
    }
    rs[t] = s; rss[t] = ss;
    __syncthreads();
    if (t < 32) {
      float a = 0.f, b = 0.f;
      for (int g2 = 0; g2 < 8; ++g2) { a += rs[t + g2 * 32]; b += rss[t + g2 * 32]; }
      atomicAdd(&ksum[bh * 32 + t], a);
      atomicAdd(&kss[bh * 32 + t], b);
    }
  } else {
    const unsigned short* base = vhb + (size_t)bh * 131072 + (size_t)seg * 512 * 32;
    float s = 0.f;
    for (int i = 0; i < 64; ++i) s += b2f(base[(size_t)(g + i * 8) * 32 + d]);
    rs[t] = s;
    __syncthreads();
    if (t < 32) {
      float a = 0.f;
      for (int g2 = 0; g2 < 8; ++g2) a += rs[t + g2 * 32];
      vcs[seg * 1024 + bh * 32 + t] = a;
    }
  }
}

__global__ __launch_bounds__(256) void kfinal(const float* __restrict__ ksum,
    const float* __restrict__ kss, float* __restrict__ krstd)
{
  int i = blockIdx.x * 256 + threadIdx.x;
  float m = ksum[i] * (1.f / 4096.f);
  float var = kss[i] * (1.f / 4096.f) - m * m;
  krstd[i] = rsqrtf(var + 1e-5f);
}

// ---------- pack V head-major -> frag-major, with colmap k-permutation ----------
// colmap(kappa) = (kappa>>2) + 16*(kappa&3) — must match attn6's packed P store.
__global__ __launch_bounds__(256) void vpack(const unsigned short* __restrict__ vh,
    unsigned short* __restrict__ vfrag)
{
  __shared__ unsigned short vt[256][42];
  const int bh = blockIdx.x >> 4, slab = blockIdx.x & 15;
  const unsigned short* src = vh + ((size_t)bh * 4096 + slab * 256) * 32;
  const int t = threadIdx.x;
#pragma unroll
  for (int i = 0; i < 4; ++i) {
    int p = i * 256 + t;
    int n = p >> 2, piece = p & 3;
    uint4 v = *(const uint4*)(src + (size_t)n * 32 + piece * 8);
    unsigned int* lrow = (unsigned int*)&vt[n][piece * 8];
    lrow[0] = v.x; lrow[1] = v.y; lrow[2] = v.z; lrow[3] = v.w;
  }
  __syncthreads();
#pragma unroll
  for (int i = 0; i < 4; ++i) {
    int op = i * 256 + t;
    int lanep = op & 63, rest = op >> 6;
    int dvt = rest & 1, kh2 = (rest >> 1) & 1, chunkl = rest >> 2;
    int lq = lanep >> 4, ll = lanep & 15;
    unsigned short o[8];
#pragma unroll
    for (int j = 0; j < 8; ++j) {
      int kappa = kh2 * 32 + lq * 8 + j;
      int nloc = (kappa >> 2) + 16 * (kappa & 3);     // colmap
      o[j] = vt[chunkl * 64 + nloc][dvt * 16 + ll];
    }
    size_t dst = ((((size_t)bh * 64 + slab * 4 + chunkl) * 2 + kh2) * 2 + dvt) * 512 + lanep * 8;
    *(bf16x8*)(vfrag + dst) = *(const bf16x8*)o;
  }
}

// ---------- MFMA flash attention v6: 1024 blocks (4/CU), async KV staging,
// wave = 32 l-rows (lf=2), per-lf ps, packed P store, float2 po ----------
// grid (32, 8, 4) = (bh, lsuper, quarter); block 256
__global__ __launch_bounds__(256, 4) void attn6(const unsigned short* __restrict__ qbuf,
    const unsigned short* __restrict__ khb, const unsigned short* __restrict__ vfrag,
    const float* __restrict__ krstd, const float* __restrict__ vcs,
    float* __restrict__ po, float* __restrict__ pd)
{
  const int bh = blockIdx.x, b = bh >> 3, h = bh & 7;
  const int lsuper = blockIdx.y, quarter = blockIdx.z;
  const int tid = threadIdx.x, w = tid >> 6, lane = tid & 63;
  const int quad = lane >> 4, l15 = lane & 15;

  __shared__ unsigned short kb_s[2][2048];
  __shared__ unsigned short vb_s[2][2048];
  __shared__ unsigned short ps[4][2][16][72];   // [wave][lf][row][kappa]

  // Q A-frags with krstd * (1/16) * log2(e) folded in (softmax base-2)
  bf16x8 qa[2];
  {
    float fold[8];
    const float* rp = krstd + bh * 32 + quad * 8;
#pragma unroll
    for (int j = 0; j < 8; ++j) fold[j] = rp[j] * (0.0625f * 1.44269504f);
#pragma unroll
    for (int lf = 0; lf < 2; ++lf) {
      int l = lsuper * 128 + w * 32 + lf * 16 + l15;
      bf16x8 qr = *(const bf16x8*)(qbuf + ((size_t)(b * NL + l)) * 256 + h * 32 + quad * 8);
      const unsigned short* qq = (const unsigned short*)&qr;
      unsigned short tmp[8];
#pragma unroll
      for (int j = 0; j < 8; ++j) tmp[j] = f2b(b2f(qq[j]) * fold[j]);
      qa[lf] = *(const bf16x8*)tmp;
    }
  }

  float drow[2][4];
  f32x4 acc[2][2];
#pragma unroll
  for (int lf = 0; lf < 2; ++lf) {
#pragma unroll
    for (int r = 0; r < 4; ++r) drow[lf][r] = 0.f;
    acc[lf][0] = (f32x4){0.f,0.f,0.f,0.f};
    acc[lf][1] = (f32x4){0.f,0.f,0.f,0.f};
  }

  const unsigned short* kcbase = khb + (size_t)bh * 131072 + (size_t)quarter * 1024 * 32;
  const unsigned short* vcbase = vfrag + (size_t)bh * 131072 + (size_t)quarter * 16 * 2048;

  // prologue: async-stage chunk 0 into buf 0
  async_load16(kcbase + tid * 8, &kb_s[0][tid * 8]);
  async_load16(vcbase + tid * 8, &vb_s[0][tid * 8]);

  for (int c = 0; c < 16; ++c) {
    const int cur = c & 1;
    __syncthreads();                       // buf[cur] DMA complete
    if (c < 15) {                          // prefetch c+1: in flight during compute
      async_load16(kcbase + (c + 1) * 2048 + tid * 8, &kb_s[cur ^ 1][tid * 8]);
      async_load16(vcbase + (c + 1) * 2048 + tid * 8, &vb_s[cur ^ 1][tid * 8]);
    }

    bf16x8 kb[4];
#pragma unroll
    for (int t = 0; t < 4; ++t)
      kb[t] = *(const bf16x8*)&kb_s[cur][(t * 16 + l15) * 32 + quad * 8];
    bf16x8 vb[4];
#pragma unroll
    for (int i = 0; i < 4; ++i)
      vb[i] = *(const bf16x8*)&vb_s[cur][i * 512 + lane * 8];

    f32x4 z = (f32x4){0.f,0.f,0.f,0.f};
#pragma unroll
    for (int lf = 0; lf < 2; ++lf) {
      f32x4 sv[4];
#pragma unroll
      for (int t = 0; t < 4; ++t) sv[t] = MFMA16(qa[lf], kb[t], z, 0, 0, 0);
#pragma unroll
      for (int r = 0; r < 4; ++r) {
        // e_t for col l15+16t == kappa 4*l15+t; packed b64 store (rtz)
        union { float f; unsigned int u; } e0, e1, e2, e3;
        float x0 = __ocml_native_exp2_f32(sv[0][r]);
        float x1 = __ocml_native_exp2_f32(sv[1][r]);
        float x2 = __ocml_native_exp2_f32(sv[2][r]);
        float x3 = __ocml_native_exp2_f32(sv[3][r]);
        drow[lf][r] += (x0 + x1) + (x2 + x3);
        e0.f = x0 - 1.0f; e1.f = x1 - 1.0f; e2.f = x2 - 1.0f; e3.f = x3 - 1.0f;
        uint2 pk;
        pk.x = (e0.u >> 16) | (e1.u & 0xFFFF0000u);
        pk.y = (e2.u >> 16) | (e3.u & 0xFFFF0000u);
        *(uint2*)&ps[w][lf][quad * 4 + r][l15 * 4] = pk;
      }
      asm volatile("s_waitcnt lgkmcnt(0)" ::: "memory");   // this wave's P stores visible
#pragma unroll
      for (int kh2 = 0; kh2 < 2; ++kh2) {
        bf16x8 pa = *(const bf16x8*)&ps[w][lf][l15][kh2 * 32 + quad * 8];
#pragma unroll
        for (int dvt = 0; dvt < 2; ++dvt)
          acc[lf][dvt] = MFMA16(pa, vb[kh2 * 2 + dvt], acc[lf][dvt], 0, 0, 0);
      }
    }
  }

  // centered-P correction: quarter column-sum of V = two eighth-sums
  const float* vc0 = vcs + (quarter * 2) * 1024 + bh * 32;
  const float* vc1 = vc0 + 1024;
  float cs0 = vc0[l15] + vc1[l15];
  float cs1 = vc0[16 + l15] + vc1[16 + l15];
#pragma unroll
  for (int lf = 0; lf < 2; ++lf)
#pragma unroll
    for (int r = 0; r < 4; ++r) {
      acc[lf][0][r] += cs0;
      acc[lf][1][r] += cs1;
    }

  // write partials; po col layout interleaved: col' = l15*2 + dvt
  const size_t PDo = (size_t)quarter * 32768 + (size_t)bh * 1024;
#pragma unroll
  for (int lf = 0; lf < 2; ++lf) {
#pragma unroll
    for (int r = 0; r < 4; ++r) {
      float sv = drow[lf][r];
      sv += __shfl_xor(sv, 1, 16);
      sv += __shfl_xor(sv, 2, 16);
      sv += __shfl_xor(sv, 4, 16);
      sv += __shfl_xor(sv, 8, 16);
      int l = lsuper * 128 + w * 32 + lf * 16 + quad * 4 + r;
      float2 val; val.x = acc[lf][0][r]; val.y = acc[lf][1][r];
      *(float2*)(po + (PDo + l) * 32 + l15 * 2) = val;
      if (l15 == 0) pd[PDo + l] = sv;
    }
  }
}

// ---------- combine 4 n-quarters -> ao hi/lo bf16 ----------
__global__ __launch_bounds__(256) void combine4(const float* __restrict__ po,
    const float* __restrict__ pd, unsigned short* __restrict__ aoh,
    unsigned short* __restrict__ aol)
{
  int gid = blockIdx.x * 256 + threadIdx.x;
  int dv = gid & 31, l = (gid >> 5) & (NL - 1), h = (gid >> 15) & 7, b = gid >> 18;
  int c = ((dv & 15) << 1) | (dv >> 4);     // inverse of interleaved po layout
  size_t r = ((size_t)(b * 8 + h)) * 1024 + l;
  float d = 0.f, o = 0.f;
#pragma unroll
  for (int q = 0; q < 4; ++q) {
    size_t rr = (size_t)q * 32768 + r;
    d += pd[rr];
    o += po[rr * 32 + c];
  }
  o = o / d;
  unsigned short hi = f2b(o);
  size_t idx = ((size_t)(b * NL) + l) * 256 + h * 32 + dv;
  aoh[idx] = hi;
  aol[idx] = f2b(o - b2f(hi));
}

// ---------- proj GEMM via MFMA hi/lo (3 passes), K=256. grid (64, 2) ----------
__global__ __launch_bounds__(256) void gemm_proj(
    const unsigned short* __restrict__ aoh, const unsigned short* __restrict__ aol,
    const unsigned short* __restrict__ wwh, const unsigned short* __restrict__ wwl,
    const float* __restrict__ bw, float* __restrict__ pj)
{
  __shared__ unsigned short As[64 * 32];
  __shared__ unsigned short Bs[128 * 32];
  const int bm = blockIdx.x * 64, bn = blockIdx.y * 128;
  const int tid = threadIdx.x, w = tid >> 6, lane = tid & 63;
  const int quad = lane >> 4, l15 = lane & 15;
  const int wr = w >> 1, wc = w & 1;
  const int arow = tid >> 2, apiece = (tid & 3) * 8;

  f32x4 acc[2][4];
#pragma unroll
  for (int i = 0; i < 2; ++i)
#pragma unroll
    for (int j = 0; j < 4; ++j) acc[i][j] = (f32x4){0.f, 0.f, 0.f, 0.f};

  for (int pair = 0; pair < 3; ++pair) {
    const unsigned short* A = (pair == 1) ? aol : aoh;
    const unsigned short* Bm = (pair == 2) ? wwl : wwh;
    for (int kt = 0; kt < 8; ++kt) {
      int k0 = kt * 32;
      __syncthreads();
      *(bf16x8*)&As[tid * 8] = *(const bf16x8*)(A + (size_t)(bm + arow) * 256 + k0 + apiece);
#pragma unroll
      for (int it = 0; it < 2; ++it) {
        int p = tid + it * 256;
        int brow = p >> 2, bpiece = (p & 3) * 8;
        *(bf16x8*)&Bs[p * 8] = *(const bf16x8*)(Bm + (size_t)(bn + brow) * 256 + k0 + bpiece);
      }
      __syncthreads();
      bf16x8 af[2], bf[4];
#pragma unroll
      for (int fr = 0; fr < 2; ++fr)
        af[fr] = *(const bf16x8*)&As[(wr * 32 + fr * 16 + l15) * 32 + quad * 8];
#pragma unroll
      for (int fc = 0; fc < 4; ++fc)
        bf[fc] = *(const bf16x8*)&Bs[(wc * 64 + fc * 16 + l15) * 32 + quad * 8];
#pragma unroll
      for (int fr = 0; fr < 2; ++fr)
#pragma unroll
        for (int fc = 0; fc < 4; ++fc)
          acc[fr][fc] = MFMA16(af[fr], bf[fc], acc[fr][fc], 0, 0, 0);
    }
  }

#pragma unroll
  for (int fr = 0; fr < 2; ++fr)
#pragma unroll
    for (int fc = 0; fc < 4; ++fc) {
      int col = bn + wc * 64 + fc * 16 + l15;
      float bb = bw[col];
#pragma unroll
      for (int r = 0; r < 4; ++r) {
        int row = bm + wr * 32 + fr * 16 + quad * 4 + r;
        pj[(size_t)row * 256 + col] = acc[fr][fc][r] + bb;
      }
    }
}

// ---------- proj instance-norm stats. grid (B, 64), 16 rows/block ----------
__global__ __launch_bounds__(256) void stats_kernel(const float* __restrict__ X,
    long batchStride, int rowsPerBlock,
    float* __restrict__ sum, float* __restrict__ sumsq)
{
  const int b = blockIdx.x, c = threadIdx.x;
  const long r0 = (long)blockIdx.y * rowsPerBlock;
  const float* base = X + (long)b * batchStride + r0 * 256 + c;
  float s = 0.f, ss = 0.f;
  for (int r = 0; r < rowsPerBlock; ++r) {
    float v = base[(long)r * 256];
    s += v; ss += v * v;
  }
  atomicAdd(&sum[b * 256 + c], s);
  atomicAdd(&sumsq[b * 256 + c], ss);
}

__global__ __launch_bounds__(256) void finalize_stats(const float* __restrict__ sum,
    const float* __restrict__ sumsq, float invR,
    float* __restrict__ mean, float* __restrict__ rstd)
{
  int i = blockIdx.x * 256 + threadIdx.x;
  float m = sum[i] * invR;
  float v = sumsq[i] * invR - m * m;
  mean[i] = m;
  rstd[i] = rsqrtf(v + 1e-5f);
}

__global__ __launch_bounds__(256) void final_out(const float* __restrict__ proj,
    const float* __restrict__ mean, const float* __restrict__ rstd,
    float* __restrict__ out)
{
  const int b = blockIdx.x, o = threadIdx.x;
  const int l1 = blockIdx.y * 16;
  const float m = mean[b * 256 + o], r = rstd[b * 256 + o];
  for (int i = 0; i < 16; ++i) {
    size_t idx = ((size_t)(b * NL + l1 + i)) * 256 + o;
    out[idx] = (proj[idx] - m) * r;
  }
}

extern "C" void kernel_launch(void* const* d_in, const int* in_sizes, int n_in,
                              void* d_out, int out_size, void* d_ws, size_t ws_size,
                              hipStream_t stream)
{
  const float* l  = (const float*)d_in[0];
  const float* x  = (const float*)d_in[1];
  const float* Wq = (const float*)d_in[2];
  const float* bq = (const float*)d_in[3];
  const float* Wk = (const float*)d_in[4];
  const float* bk = (const float*)d_in[5];
  const float* Wv = (const float*)d_in[6];
  const float* bv = (const float*)d_in[7];
  const float* Ww = (const float*)d_in[8];
  const float* bw = (const float*)d_in[9];
  float* out = (float*)d_out;

  unsigned short* up = (unsigned short*)d_ws;
  unsigned short* xbf   = up;                         // 8,388,608
  unsigned short* lbf   = xbf   + 8388608;            // 2,097,152
  unsigned short* wkb   = lbf   + 2097152;            // 131,072
  unsigned short* wvb   = wkb   + 131072;
  unsigned short* wqb   = wvb   + 131072;
  unsigned short* qbuf  = wqb   + 131072;             // 1,048,576
  unsigned short* khb   = qbuf  + 1048576;            // 4,194,304
  unsigned short* vhb   = khb   + 4194304;
  unsigned short* vfrag = vhb   + 4194304;
  unsigned short* aoh   = vfrag + 4194304;            // 1,048,576
  unsigned short* aol   = aoh   + 1048576;
  unsigned short* wwh   = aol   + 1048576;            // 65,536
  unsigned short* wwl   = wwh   + 65536;
  // ushort total = 26,738,688 -> 53,477,376 bytes
  float* F     = (float*)((char*)d_ws + 53477376);
  float* krstd = F;                                   // 1024
  float* vcs   = krstd + 1024;                        // 8192
  float* po    = vcs + 8192;                          // 4 * 1,048,576
  float* pd    = po + 4194304;                        // 131,072
  float* pj    = pd + 131072;                         // 1,048,576
  float* st    = pj + 1048576;                        // 6144
  float* ksum  = st;          float* kss   = st + 1024;
  float* psum  = st + 2048;   float* psq   = st + 3072;
  float* pmean = st + 4096;   float* prstd = st + 5120;

  hipMemsetAsync(st, 0, 4096 * sizeof(float), stream);

  dim3 blk(256);
  conv_bf16<<<8192, blk, 0, stream>>>(x,  xbf, 8388608);
  conv_bf16<<<2048, blk, 0, stream>>>(l,  lbf, 2097152);
  conv_w4<<<dim3(128, 4), blk, 0, stream>>>(Wk, Wv, Wq, Ww, wkb, wvb, wqb, wwh, wwl);
  gemm128<<<576, blk, 0, stream>>>(xbf, lbf, wkb, wvb, wqb, bk, bv, bq, khb, vhb, qbuf);
  kvstats<<<dim3(64, 8), blk, 0, stream>>>(khb, vhb, ksum, kss, vcs);
  kfinal<<<4, blk, 0, stream>>>(ksum, kss, krstd);
  vpack<<<512, blk, 0, stream>>>(vhb, vfrag);
  attn6<<<dim3(32, 8, 4), blk, 0, stream>>>(qbuf, khb, vfrag, krstd, vcs, po, pd);
  combine4<<<4096, blk, 0, stream>>>(po, pd, aoh, aol);
  gemm_proj<<<dim3(64, 2), blk, 0, stream>>>(aoh, aol, wwh, wwl, bw, pj);
  stats_kernel<<<dim3(4, 64), blk, 0, stream>>>(pj, (long)NL * 256, 16, psum, psq);
  finalize_stats<<<4, blk, 0, stream>>>(psum, psq, 1.0f / NL, pmean, prstd);
  final_out<<<dim3(4, 64), blk, 0, stream>>>(pj, pmean, prstd, out);
}